// Round 1
// baseline (965.491 us; speedup 1.0000x reference)
//
#include <hip/hip_runtime.h>
#include <math.h>

#define NSLOPE 0.2f

static __device__ __forceinline__ float leaky(float e) {
    return e > 0.f ? e : NSLOPE * e;
}

// ---------------- CSR build ----------------

__global__ void k_set1(int* __restrict__ c, int N) {
    int i = blockIdx.x * blockDim.x + threadIdx.x;
    if (i < N) c[i] = 1;   // self-loop counts as one incoming edge
}

__global__ void k_count(const int* __restrict__ dst, int* __restrict__ cnt, int E) {
    int i = blockIdx.x * blockDim.x + threadIdx.x;
    if (i < E) atomicAdd(&cnt[dst[i]], 1);
}

// 1024 elements per block (256 threads x 4)
__global__ void k_scan_local(const int* __restrict__ cnt, int* __restrict__ ptr,
                             int* __restrict__ bsum, int N) {
    __shared__ int sd[256];
    int t = threadIdx.x;
    int i0 = blockIdx.x * 1024 + t * 4;
    int v0 = (i0 + 0 < N) ? cnt[i0 + 0] : 0;
    int v1 = (i0 + 1 < N) ? cnt[i0 + 1] : 0;
    int v2 = (i0 + 2 < N) ? cnt[i0 + 2] : 0;
    int v3 = (i0 + 3 < N) ? cnt[i0 + 3] : 0;
    int ts = v0 + v1 + v2 + v3;
    sd[t] = ts;
    __syncthreads();
    for (int o = 1; o < 256; o <<= 1) {
        int add = (t >= o) ? sd[t - o] : 0;
        __syncthreads();
        sd[t] += add;
        __syncthreads();
    }
    int run = sd[t] - ts;  // exclusive within chunk
    if (i0 + 0 < N) ptr[i0 + 0] = run; run += v0;
    if (i0 + 1 < N) ptr[i0 + 1] = run; run += v1;
    if (i0 + 2 < N) ptr[i0 + 2] = run; run += v2;
    if (i0 + 3 < N) ptr[i0 + 3] = run;
    if (t == 255) bsum[blockIdx.x] = sd[255];
}

__global__ void k_scan_bsums(int* __restrict__ bsum, int nb) {
    if (threadIdx.x == 0 && blockIdx.x == 0) {
        int run = 0;
        for (int b = 0; b < nb; ++b) { int t = bsum[b]; bsum[b] = run; run += t; }
    }
}

__global__ void k_scan_add(int* __restrict__ ptr, const int* __restrict__ bsum,
                           int N, int Et) {
    int i = blockIdx.x * blockDim.x + threadIdx.x;
    if (i < N) ptr[i] += bsum[i >> 10];
    else if (i == N) ptr[N] = Et;
}

__global__ void k_copy(int* __restrict__ d, const int* __restrict__ s, int N) {
    int i = blockIdx.x * blockDim.x + threadIdx.x;
    if (i < N) d[i] = s[i];
}

__global__ void k_fillcsr(const int* __restrict__ ei, int* __restrict__ fptr,
                          int* __restrict__ srcs, int E, int Et) {
    int i = blockIdx.x * blockDim.x + threadIdx.x;
    if (i >= Et) return;
    int s, d;
    if (i < E) { s = ei[i]; d = ei[E + i]; }
    else       { s = d = i - E; }               // self loop
    int pos = atomicAdd(&fptr[d], 1);
    srcs[pos] = s;
}

// ---------------- fp32 tiled GEMM: C[N,M] = A[N,K] @ B[K,M] ----------------
// BM=BN=64, BK=16, 256 threads, 4x4 micro-tile per thread.

__global__ __launch_bounds__(256) void k_gemm(const float* __restrict__ A,
                                              const float* __restrict__ B,
                                              float* __restrict__ C,
                                              int N, int K, int M) {
    __shared__ float As[16][64];   // [k][m]
    __shared__ float Bs[16][64];   // [k][n]
    const int tid = threadIdx.x;
    const int bm = blockIdx.x << 6;
    const int bn = blockIdx.y << 6;
    const int tr = tid >> 4, tc = tid & 15;
    const int lr = tid >> 2, lc4 = (tid & 3) << 2;   // A-load: 64 rows x 16 cols
    const int br = tid >> 6, bc = tid & 63;          // B-load: 16 rows x 64 cols
    const int ar = bm + lr;
    float acc[4][4] = {{0.f}};

    for (int k0 = 0; k0 < K; k0 += 16) {
        if (ar < N) {
            const float4 av = *reinterpret_cast<const float4*>(&A[(size_t)ar * K + k0 + lc4]);
            As[lc4 + 0][lr] = av.x; As[lc4 + 1][lr] = av.y;
            As[lc4 + 2][lr] = av.z; As[lc4 + 3][lr] = av.w;
        } else {
            As[lc4 + 0][lr] = 0.f; As[lc4 + 1][lr] = 0.f;
            As[lc4 + 2][lr] = 0.f; As[lc4 + 3][lr] = 0.f;
        }
#pragma unroll
        for (int rr = 0; rr < 16; rr += 4)
            Bs[br + rr][bc] = B[(size_t)(k0 + br + rr) * M + bn + bc];
        __syncthreads();
#pragma unroll
        for (int k = 0; k < 16; ++k) {
            const float4 av = *reinterpret_cast<const float4*>(&As[k][tr << 2]);
            const float4 bv = *reinterpret_cast<const float4*>(&Bs[k][tc << 2]);
            const float aa[4] = {av.x, av.y, av.z, av.w};
            const float bb[4] = {bv.x, bv.y, bv.z, bv.w};
#pragma unroll
            for (int i = 0; i < 4; ++i)
#pragma unroll
                for (int j = 0; j < 4; ++j)
                    acc[i][j] += aa[i] * bb[j];
        }
        __syncthreads();
    }

    const int row0 = bm + (tr << 2);
    const int col0 = bn + (tc << 2);
#pragma unroll
    for (int i = 0; i < 4; ++i) {
        int r = row0 + i;
        if (r < N) {
            float4 v;
            v.x = acc[i][0]; v.y = acc[i][1]; v.z = acc[i][2]; v.w = acc[i][3];
            *reinterpret_cast<float4*>(&C[(size_t)r * M + col0]) = v;
        }
    }
}

// ---------------- attention logits per node ----------------
// block = H*C threads, one node per block
__global__ void k_al(const float* __restrict__ h, const float* __restrict__ asrc,
                     const float* __restrict__ adst, float* __restrict__ als,
                     float* __restrict__ ald, int Hn, int Cn) {
    int n = blockIdx.x, t = threadIdx.x;
    int HC = Hn * Cn;
    float hv = h[(size_t)n * HC + t];
    float ps = hv * asrc[t];
    float pd = hv * adst[t];
    for (int o = Cn >> 1; o; o >>= 1) { ps += __shfl_xor(ps, o); pd += __shfl_xor(pd, o); }
    if ((t & (Cn - 1)) == 0) {
        int hd = t / Cn;
        als[n * Hn + hd] = ps;
        ald[n * Hn + hd] = pd;
    }
}

// ---------------- per-node softmax + aggregate ----------------
// block = H*C threads, one dst node per block; CSR edge list (srcs) by dst.
__global__ void k_aggregate(const float* __restrict__ h, const float* __restrict__ als,
                            const float* __restrict__ ald, const int* __restrict__ ptr,
                            const int* __restrict__ srcs, const float* __restrict__ bias,
                            float* __restrict__ out, int Hn, int Cn, int relu) {
    int n = blockIdx.x, t = threadIdx.x;
    int HC = Hn * Cn;
    int hd = t / Cn;
    int lane = t & (Cn - 1);
    int beg = ptr[n], end = ptr[n + 1];
    float aldv = ald[n * Hn + hd];

    // per-head max over incoming edges
    float m = -1e30f;
    for (int j = beg + lane; j < end; j += Cn) {
        float e = leaky(als[srcs[j] * Hn + hd] + aldv);
        m = fmaxf(m, e);
    }
    for (int o = Cn >> 1; o; o >>= 1) m = fmaxf(m, __shfl_xor(m, o));

    // per-head sum of exp
    float ssum = 0.f;
    for (int j = beg + lane; j < end; j += Cn) {
        float e = leaky(als[srcs[j] * Hn + hd] + aldv);
        ssum += expf(e - m);
    }
    for (int o = Cn >> 1; o; o >>= 1) ssum += __shfl_xor(ssum, o);
    float inv = 1.f / (ssum + 1e-16f);

    // weighted aggregation; thread t owns channel t of this node
    float acc = 0.f;
    for (int j = beg; j < end; ++j) {
        int s = srcs[j];
        float e = leaky(als[s * Hn + hd] + aldv);
        float alpha = expf(e - m) * inv;
        acc += alpha * h[(size_t)s * HC + t];
    }
    float v = acc + bias[t];
    if (relu) v = fmaxf(v, 0.f);
    out[(size_t)n * HC + t] = v;
}

// ---------------- launch ----------------

extern "C" void kernel_launch(void* const* d_in, const int* in_sizes, int n_in,
                              void* d_out, int out_size, void* d_ws, size_t ws_size,
                              hipStream_t stream) {
    const float* x   = (const float*)d_in[0];
    const int*   ei  = (const int*)d_in[1];
    const float* W1  = (const float*)d_in[2];
    const float* as1 = (const float*)d_in[3];
    const float* ad1 = (const float*)d_in[4];
    const float* b1  = (const float*)d_in[5];
    const float* W2  = (const float*)d_in[6];
    const float* as2 = (const float*)d_in[7];
    const float* ad2 = (const float*)d_in[8];
    const float* b2  = (const float*)d_in[9];
    const float* W3  = (const float*)d_in[10];
    const float* as3 = (const float*)d_in[11];
    const float* ad3 = (const float*)d_in[12];
    const float* b3  = (const float*)d_in[13];

    const int F  = 256;
    const int N  = in_sizes[0] / F;     // 50000
    const int E  = in_sizes[1] / 2;     // 800000
    const int Et = E + N;               // + self loops

    char* w = (char*)d_ws;
    auto alloc = [&](size_t bytes) {
        char* p = w;
        w += (bytes + 255) & ~(size_t)255;
        return p;
    };
    float* bufG = (float*)alloc((size_t)N * F * 4);   // gemm output h
    float* bufA = (float*)alloc((size_t)N * F * 4);   // layer output
    float* als  = (float*)alloc((size_t)N * 8 * 4);
    float* ald  = (float*)alloc((size_t)N * 8 * 4);
    int*   cnt  = (int*)alloc((size_t)N * 4);
    int*   ptr  = (int*)alloc((size_t)(N + 1) * 4);
    int*   fptr = (int*)alloc((size_t)(N + 1) * 4);
    int*   srcs = (int*)alloc((size_t)Et * 4);
    int*   bsum = (int*)alloc(4096);

    // ---- CSR build (by dst) ----
    const int nb = (N + 1023) / 1024;
    hipLaunchKernelGGL(k_set1,      dim3((N + 255) / 256),  dim3(256), 0, stream, cnt, N);
    hipLaunchKernelGGL(k_count,     dim3((E + 255) / 256),  dim3(256), 0, stream, ei + E, cnt, E);
    hipLaunchKernelGGL(k_scan_local,dim3(nb),               dim3(256), 0, stream, cnt, ptr, bsum, N);
    hipLaunchKernelGGL(k_scan_bsums,dim3(1),                dim3(64),  0, stream, bsum, nb);
    hipLaunchKernelGGL(k_scan_add,  dim3((N + 256) / 256),  dim3(256), 0, stream, ptr, bsum, N, Et);
    hipLaunchKernelGGL(k_copy,      dim3((N + 255) / 256),  dim3(256), 0, stream, fptr, ptr, N);
    hipLaunchKernelGGL(k_fillcsr,   dim3((Et + 255) / 256), dim3(256), 0, stream, ei, fptr, srcs, E, Et);

    auto layer = [&](const float* in, const float* W, int M, const float* as_,
                     const float* ad_, const float* b_, float* out,
                     int Hn, int Cn, int relu) {
        dim3 g((N + 63) / 64, M / 64);
        hipLaunchKernelGGL(k_gemm, g, dim3(256), 0, stream, in, W, bufG, N, F, M);
        hipLaunchKernelGGL(k_al, dim3(N), dim3(Hn * Cn), 0, stream,
                           bufG, as_, ad_, als, ald, Hn, Cn);
        hipLaunchKernelGGL(k_aggregate, dim3(N), dim3(Hn * Cn), 0, stream,
                           bufG, als, ald, ptr, srcs, b_, out, Hn, Cn, relu);
    };

    layer(x,    W1, 256, as1, ad1, b1, bufA,           8, 32, 1);
    layer(bufA, W2, 256, as2, ad2, b2, bufA,           8, 32, 1);
    layer(bufA, W3,  64, as3, ad3, b3, (float*)d_out,  1, 64, 0);
}

// Round 2
// 703.233 us; speedup vs baseline: 1.3729x; 1.3729x over previous
//
#include <hip/hip_runtime.h>
#include <math.h>

#define NSLOPE 0.2f

static __device__ __forceinline__ float leaky(float e) {
    return e > 0.f ? e : NSLOPE * e;
}

// ---------------- CSR build ----------------

__global__ void k_set1(int* __restrict__ c, int N) {
    int i = blockIdx.x * blockDim.x + threadIdx.x;
    if (i < N) c[i] = 1;   // self-loop counts as one incoming edge
}

__global__ void k_count(const int* __restrict__ dst, int* __restrict__ cnt, int E) {
    int i = blockIdx.x * blockDim.x + threadIdx.x;
    if (i < E) atomicAdd(&cnt[dst[i]], 1);
}

// 1024 elements per block (256 threads x 4)
__global__ void k_scan_local(const int* __restrict__ cnt, int* __restrict__ ptr,
                             int* __restrict__ bsum, int N) {
    __shared__ int sd[256];
    int t = threadIdx.x;
    int i0 = blockIdx.x * 1024 + t * 4;
    int v0 = (i0 + 0 < N) ? cnt[i0 + 0] : 0;
    int v1 = (i0 + 1 < N) ? cnt[i0 + 1] : 0;
    int v2 = (i0 + 2 < N) ? cnt[i0 + 2] : 0;
    int v3 = (i0 + 3 < N) ? cnt[i0 + 3] : 0;
    int ts = v0 + v1 + v2 + v3;
    sd[t] = ts;
    __syncthreads();
    for (int o = 1; o < 256; o <<= 1) {
        int add = (t >= o) ? sd[t - o] : 0;
        __syncthreads();
        sd[t] += add;
        __syncthreads();
    }
    int run = sd[t] - ts;  // exclusive within chunk
    if (i0 + 0 < N) ptr[i0 + 0] = run; run += v0;
    if (i0 + 1 < N) ptr[i0 + 1] = run; run += v1;
    if (i0 + 2 < N) ptr[i0 + 2] = run; run += v2;
    if (i0 + 3 < N) ptr[i0 + 3] = run;
    if (t == 255) bsum[blockIdx.x] = sd[255];
}

__global__ void k_scan_bsums(int* __restrict__ bsum, int nb) {
    if (threadIdx.x == 0 && blockIdx.x == 0) {
        int run = 0;
        for (int b = 0; b < nb; ++b) { int t = bsum[b]; bsum[b] = run; run += t; }
    }
}

__global__ void k_scan_add(int* __restrict__ ptr, const int* __restrict__ bsum,
                           int N, int Et) {
    int i = blockIdx.x * blockDim.x + threadIdx.x;
    if (i < N) ptr[i] += bsum[i >> 10];
    else if (i == N) ptr[N] = Et;
}

__global__ void k_copy(int* __restrict__ d, const int* __restrict__ s, int N) {
    int i = blockIdx.x * blockDim.x + threadIdx.x;
    if (i < N) d[i] = s[i];
}

__global__ void k_fillcsr(const int* __restrict__ ei, int* __restrict__ fptr,
                          int* __restrict__ srcs, int E, int Et) {
    int i = blockIdx.x * blockDim.x + threadIdx.x;
    if (i >= Et) return;
    int s, d;
    if (i < E) { s = ei[i]; d = ei[E + i]; }
    else       { s = d = i - E; }               // self loop
    int pos = atomicAdd(&fptr[d], 1);
    srcs[pos] = s;
}

// ---------------- fp32 tiled GEMM: C[N,M] = A[N,K] @ B[K,M] ----------------
// BM=BN=64, BK=16, 256 threads, 4x4 micro-tile per thread.

__global__ __launch_bounds__(256) void k_gemm(const float* __restrict__ A,
                                              const float* __restrict__ B,
                                              float* __restrict__ C,
                                              int N, int K, int M) {
    __shared__ float As[16][64];   // [k][m]
    __shared__ float Bs[16][64];   // [k][n]
    const int tid = threadIdx.x;
    const int bm = blockIdx.x << 6;
    const int bn = blockIdx.y << 6;
    const int tr = tid >> 4, tc = tid & 15;
    const int lr = tid >> 2, lc4 = (tid & 3) << 2;   // A-load: 64 rows x 16 cols
    const int br = tid >> 6, bc = tid & 63;          // B-load: 16 rows x 64 cols
    const int ar = bm + lr;
    float acc[4][4] = {{0.f}};

    for (int k0 = 0; k0 < K; k0 += 16) {
        if (ar < N) {
            const float4 av = *reinterpret_cast<const float4*>(&A[(size_t)ar * K + k0 + lc4]);
            As[lc4 + 0][lr] = av.x; As[lc4 + 1][lr] = av.y;
            As[lc4 + 2][lr] = av.z; As[lc4 + 3][lr] = av.w;
        } else {
            As[lc4 + 0][lr] = 0.f; As[lc4 + 1][lr] = 0.f;
            As[lc4 + 2][lr] = 0.f; As[lc4 + 3][lr] = 0.f;
        }
#pragma unroll
        for (int rr = 0; rr < 16; rr += 4)
            Bs[br + rr][bc] = B[(size_t)(k0 + br + rr) * M + bn + bc];
        __syncthreads();
#pragma unroll
        for (int k = 0; k < 16; ++k) {
            const float4 av = *reinterpret_cast<const float4*>(&As[k][tr << 2]);
            const float4 bv = *reinterpret_cast<const float4*>(&Bs[k][tc << 2]);
            const float aa[4] = {av.x, av.y, av.z, av.w};
            const float bb[4] = {bv.x, bv.y, bv.z, bv.w};
#pragma unroll
            for (int i = 0; i < 4; ++i)
#pragma unroll
                for (int j = 0; j < 4; ++j)
                    acc[i][j] += aa[i] * bb[j];
        }
        __syncthreads();
    }

    const int row0 = bm + (tr << 2);
    const int col0 = bn + (tc << 2);
#pragma unroll
    for (int i = 0; i < 4; ++i) {
        int r = row0 + i;
        if (r < N) {
            float4 v;
            v.x = acc[i][0]; v.y = acc[i][1]; v.z = acc[i][2]; v.w = acc[i][3];
            *reinterpret_cast<float4*>(&C[(size_t)r * M + col0]) = v;
        }
    }
}

// ---------------- attention logits per node ----------------
// one wave per node; lane l owns VEC channels starting at l*VEC
template <int HN, int CN, int VEC>
__global__ __launch_bounds__(256) void k_al2(const float* __restrict__ h,
                                             const float* __restrict__ asrc,
                                             const float* __restrict__ adst,
                                             float* __restrict__ als,
                                             float* __restrict__ ald, int N) {
    constexpr int HC = HN * CN;
    constexpr int LPH = CN / VEC;   // lanes per head
    const int l = threadIdx.x & 63;
    const int n = blockIdx.x * 4 + (threadIdx.x >> 6);
    if (n >= N) return;
    const int ch = l * VEC;
    float ps, pd;
    if constexpr (VEC == 4) {
        const float4 hv = *reinterpret_cast<const float4*>(&h[(size_t)n * HC + ch]);
        const float4 av = *reinterpret_cast<const float4*>(&asrc[ch]);
        const float4 dv = *reinterpret_cast<const float4*>(&adst[ch]);
        ps = hv.x * av.x + hv.y * av.y + hv.z * av.z + hv.w * av.w;
        pd = hv.x * dv.x + hv.y * dv.y + hv.z * dv.z + hv.w * dv.w;
    } else {
        const float hv = h[(size_t)n * HC + ch];
        ps = hv * asrc[ch];
        pd = hv * adst[ch];
    }
#pragma unroll
    for (int o = 1; o < LPH; o <<= 1) { ps += __shfl_xor(ps, o); pd += __shfl_xor(pd, o); }
    if ((l % LPH) == 0) {
        const int hd = ch / CN;
        als[n * HN + hd] = ps;
        ald[n * HN + hd] = pd;
    }
}

// ---------------- per-node softmax + aggregate (one wave per node) ----------------
// Lane l: logits for head l%HN over edges strided by 64/HN (online softmax),
// then owns channels [l*VEC, l*VEC+VEC). Alpha broadcast in-wave via shfl.
template <int HN, int CN, int VEC>
__global__ __launch_bounds__(256) void k_agg2(const float* __restrict__ h,
                                              const float* __restrict__ als,
                                              const float* __restrict__ ald,
                                              const int* __restrict__ ptr,
                                              const int* __restrict__ srcs,
                                              const float* __restrict__ bias,
                                              float* __restrict__ out,
                                              int N, int relu) {
    constexpr int HC = HN * CN;
    constexpr int SUBS = 64 / HN;    // edge-strided lanes per head
    constexpr int CH = 64 / HN;      // edges handled per chunk
    const int l = threadIdx.x & 63;
    const int n = blockIdx.x * 4 + (threadIdx.x >> 6);
    if (n >= N) return;
    const int beg = ptr[n], end = ptr[n + 1];
    const int hd_e = l % HN;         // head this lane computes logits for
    const int sub = l / HN;
    const float aldv = ald[n * HN + hd_e];

    // ---- online softmax (max + sum in one edge pass) ----
    float m = -1e30f, ssum = 0.f;
    for (int j = beg + sub; j < end; j += SUBS) {
        const float e = leaky(als[srcs[j] * HN + hd_e] + aldv);
        if (e > m) { ssum = ssum * __expf(m - e) + 1.f; m = e; }
        else        ssum += __expf(e - m);
    }
#pragma unroll
    for (int o = HN; o < 64; o <<= 1) {
        const float m2 = __shfl_xor(m, o), s2 = __shfl_xor(ssum, o);
        const float mn = fmaxf(m, m2);
        ssum = ssum * __expf(m - mn) + s2 * __expf(m2 - mn);
        m = mn;
    }
    const float inv = 1.f / (ssum + 1e-16f);

    // ---- weighted aggregation ----
    const int ch = l * VEC;          // first channel this lane owns
    const int hl = ch / CN;          // head of owned channels
    float acc[VEC];
#pragma unroll
    for (int v = 0; v < VEC; ++v) acc[v] = 0.f;

    for (int j0 = beg; j0 < end; j0 += CH) {
        const int j = j0 + sub;
        int sreg = 0;
        float alpha = 0.f;
        if (j < end) {
            sreg = srcs[j];
            const float e = leaky(als[sreg * HN + hd_e] + aldv);
            alpha = __expf(e - m) * inv;
        }
        const int cc = min(CH, end - j0);
        for (int c = 0; c < cc; ++c) {
            const int s   = __shfl(sreg, c * HN);            // src of edge c
            const float a = __shfl(alpha, c * HN + hl);      // alpha[edge c][my head]
            const float* hp = &h[(size_t)s * HC + ch];
            if constexpr (VEC == 4) {
                const float4 hv = *reinterpret_cast<const float4*>(hp);
                acc[0] += a * hv.x; acc[1] += a * hv.y;
                acc[2] += a * hv.z; acc[3] += a * hv.w;
            } else {
                acc[0] += a * hp[0];
            }
        }
    }

#pragma unroll
    for (int v = 0; v < VEC; ++v) {
        float o = acc[v] + bias[ch + v];
        if (relu) o = fmaxf(o, 0.f);
        acc[v] = o;
    }
    if constexpr (VEC == 4) {
        float4 vout;
        vout.x = acc[0]; vout.y = acc[1]; vout.z = acc[2]; vout.w = acc[3];
        *reinterpret_cast<float4*>(&out[(size_t)n * HC + ch]) = vout;
    } else {
        out[(size_t)n * HC + ch] = acc[0];
    }
}

// ---------------- launch ----------------

extern "C" void kernel_launch(void* const* d_in, const int* in_sizes, int n_in,
                              void* d_out, int out_size, void* d_ws, size_t ws_size,
                              hipStream_t stream) {
    const float* x   = (const float*)d_in[0];
    const int*   ei  = (const int*)d_in[1];
    const float* W1  = (const float*)d_in[2];
    const float* as1 = (const float*)d_in[3];
    const float* ad1 = (const float*)d_in[4];
    const float* b1  = (const float*)d_in[5];
    const float* W2  = (const float*)d_in[6];
    const float* as2 = (const float*)d_in[7];
    const float* ad2 = (const float*)d_in[8];
    const float* b2  = (const float*)d_in[9];
    const float* W3  = (const float*)d_in[10];
    const float* as3 = (const float*)d_in[11];
    const float* ad3 = (const float*)d_in[12];
    const float* b3  = (const float*)d_in[13];

    const int F  = 256;
    const int N  = in_sizes[0] / F;     // 50000
    const int E  = in_sizes[1] / 2;     // 800000
    const int Et = E + N;               // + self loops

    char* w = (char*)d_ws;
    auto alloc = [&](size_t bytes) {
        char* p = w;
        w += (bytes + 255) & ~(size_t)255;
        return p;
    };
    float* bufG = (float*)alloc((size_t)N * F * 4);   // gemm output h
    float* bufA = (float*)alloc((size_t)N * F * 4);   // layer output
    float* als  = (float*)alloc((size_t)N * 8 * 4);
    float* ald  = (float*)alloc((size_t)N * 8 * 4);
    int*   cnt  = (int*)alloc((size_t)N * 4);
    int*   ptr  = (int*)alloc((size_t)(N + 1) * 4);
    int*   fptr = (int*)alloc((size_t)(N + 1) * 4);
    int*   srcs = (int*)alloc((size_t)Et * 4);
    int*   bsum = (int*)alloc(4096);

    // ---- CSR build (by dst) ----
    const int nb = (N + 1023) / 1024;
    hipLaunchKernelGGL(k_set1,      dim3((N + 255) / 256),  dim3(256), 0, stream, cnt, N);
    hipLaunchKernelGGL(k_count,     dim3((E + 255) / 256),  dim3(256), 0, stream, ei + E, cnt, E);
    hipLaunchKernelGGL(k_scan_local,dim3(nb),               dim3(256), 0, stream, cnt, ptr, bsum, N);
    hipLaunchKernelGGL(k_scan_bsums,dim3(1),                dim3(64),  0, stream, bsum, nb);
    hipLaunchKernelGGL(k_scan_add,  dim3((N + 256) / 256),  dim3(256), 0, stream, ptr, bsum, N, Et);
    hipLaunchKernelGGL(k_copy,      dim3((N + 255) / 256),  dim3(256), 0, stream, fptr, ptr, N);
    hipLaunchKernelGGL(k_fillcsr,   dim3((Et + 255) / 256), dim3(256), 0, stream, ei, fptr, srcs, E, Et);

    const dim3 gN4((N + 3) / 4);

    // ---- layer 1: 256 -> 8x32, relu ----
    {
        dim3 g((N + 63) / 64, 256 / 64);
        hipLaunchKernelGGL(k_gemm, g, dim3(256), 0, stream, x, W1, bufG, N, F, 256);
        hipLaunchKernelGGL((k_al2<8, 32, 4>), gN4, dim3(256), 0, stream, bufG, as1, ad1, als, ald, N);
        hipLaunchKernelGGL((k_agg2<8, 32, 4>), gN4, dim3(256), 0, stream,
                           bufG, als, ald, ptr, srcs, b1, bufA, N, 1);
    }
    // ---- layer 2: 256 -> 8x32, relu ----
    {
        dim3 g((N + 63) / 64, 256 / 64);
        hipLaunchKernelGGL(k_gemm, g, dim3(256), 0, stream, bufA, W2, bufG, N, F, 256);
        hipLaunchKernelGGL((k_al2<8, 32, 4>), gN4, dim3(256), 0, stream, bufG, as2, ad2, als, ald, N);
        hipLaunchKernelGGL((k_agg2<8, 32, 4>), gN4, dim3(256), 0, stream,
                           bufG, als, ald, ptr, srcs, b2, bufA, N, 1);
    }
    // ---- layer 3: 256 -> 1x64, no relu ----
    {
        dim3 g((N + 63) / 64, 64 / 64);
        hipLaunchKernelGGL(k_gemm, g, dim3(256), 0, stream, bufA, W3, bufG, N, F, 64);
        hipLaunchKernelGGL((k_al2<1, 64, 1>), gN4, dim3(256), 0, stream, bufG, as3, ad3, als, ald, N);
        hipLaunchKernelGGL((k_agg2<1, 64, 1>), gN4, dim3(256), 0, stream,
                           bufG, als, ald, ptr, srcs, b3, (float*)d_out, N, 0);
    }
}

// Round 3
// 499.561 us; speedup vs baseline: 1.9327x; 1.4077x over previous
//
#include <hip/hip_runtime.h>
#include <math.h>

#define NSLOPE 0.2f

typedef __attribute__((ext_vector_type(8))) short bf16x8;
typedef __attribute__((ext_vector_type(4))) float f32x4;

static __device__ __forceinline__ float leaky(float e) {
    return e > 0.f ? e : NSLOPE * e;
}

static __device__ __forceinline__ float bfu(unsigned short u) {
    return __uint_as_float(((unsigned)u) << 16);
}

static __device__ __forceinline__ unsigned short f2bf_rne(float f) {
    unsigned b = __float_as_uint(f);
    unsigned r = b + 0x7fffu + ((b >> 16) & 1u);
    return (unsigned short)(r >> 16);
}

// ---------------- CSR build ----------------

__global__ void k_set1(int* __restrict__ c, int N) {
    int i = blockIdx.x * blockDim.x + threadIdx.x;
    if (i < N) c[i] = 1;
}

__global__ void k_count(const int* __restrict__ dst, int* __restrict__ cnt, int E) {
    int i = blockIdx.x * blockDim.x + threadIdx.x;
    if (i < E) atomicAdd(&cnt[dst[i]], 1);
}

__global__ void k_scan_local(const int* __restrict__ cnt, int* __restrict__ ptr,
                             int* __restrict__ bsum, int N) {
    __shared__ int sd[256];
    int t = threadIdx.x;
    int i0 = blockIdx.x * 1024 + t * 4;
    int v0 = (i0 + 0 < N) ? cnt[i0 + 0] : 0;
    int v1 = (i0 + 1 < N) ? cnt[i0 + 1] : 0;
    int v2 = (i0 + 2 < N) ? cnt[i0 + 2] : 0;
    int v3 = (i0 + 3 < N) ? cnt[i0 + 3] : 0;
    int ts = v0 + v1 + v2 + v3;
    sd[t] = ts;
    __syncthreads();
    for (int o = 1; o < 256; o <<= 1) {
        int add = (t >= o) ? sd[t - o] : 0;
        __syncthreads();
        sd[t] += add;
        __syncthreads();
    }
    int run = sd[t] - ts;
    if (i0 + 0 < N) ptr[i0 + 0] = run; run += v0;
    if (i0 + 1 < N) ptr[i0 + 1] = run; run += v1;
    if (i0 + 2 < N) ptr[i0 + 2] = run; run += v2;
    if (i0 + 3 < N) ptr[i0 + 3] = run;
    if (t == 255) bsum[blockIdx.x] = sd[255];
}

__global__ void k_scan_bsums(int* __restrict__ bsum, int nb) {
    if (threadIdx.x == 0 && blockIdx.x == 0) {
        int run = 0;
        for (int b = 0; b < nb; ++b) { int t = bsum[b]; bsum[b] = run; run += t; }
    }
}

__global__ void k_scan_add(int* __restrict__ ptr, const int* __restrict__ bsum,
                           int N, int Et) {
    int i = blockIdx.x * blockDim.x + threadIdx.x;
    if (i < N) ptr[i] += bsum[i >> 10];
    else if (i == N) ptr[N] = Et;
}

__global__ void k_copy(int* __restrict__ d, const int* __restrict__ s, int N) {
    int i = blockIdx.x * blockDim.x + threadIdx.x;
    if (i < N) d[i] = s[i];
}

__global__ void k_fillcsr(const int* __restrict__ ei, int* __restrict__ fptr,
                          int* __restrict__ srcs, int E, int Et) {
    int i = blockIdx.x * blockDim.x + threadIdx.x;
    if (i >= Et) return;
    int s, d;
    if (i < E) { s = ei[i]; d = ei[E + i]; }
    else       { s = d = i - E; }
    int pos = atomicAdd(&fptr[d], 1);
    srcs[pos] = s;
}

// ---------------- W transpose: Wt[M][K] = W[K][M] ----------------
__global__ __launch_bounds__(256) void k_transpose(const float* __restrict__ B,
                                                   float* __restrict__ Bt,
                                                   int K, int M) {
    __shared__ float tile[32][33];
    const int bx = blockIdx.x * 32;   // M offset
    const int by = blockIdx.y * 32;   // K offset
    const int tx = threadIdx.x & 31, ty = threadIdx.x >> 5;
    for (int r = ty; r < 32; r += 8) tile[r][tx] = B[(size_t)(by + r) * M + bx + tx];
    __syncthreads();
    for (int r = ty; r < 32; r += 8) Bt[(size_t)(bx + r) * K + by + tx] = tile[tx][r];
}

// ---------------- split-bf16 MFMA GEMM ----------------
// C[N,M] = A[N,256] @ W[256,M], using Wt[M][256].
// Block: 256 thr = 4 waves (2x2), tile 64x64, wave tile 32x32 (2x2 frags 16x16x32).
// A = Ahi+Alo, W = Whi+Wlo (truncated bf16 split); 3 MFMA per frag pair.
// Writes h fp32 and h bf16 (RNE).

static __device__ __forceinline__ void cvt8(float4 v0, float4 v1,
                                            bf16x8& hi, bf16x8& lo) {
    float f[8] = {v0.x, v0.y, v0.z, v0.w, v1.x, v1.y, v1.z, v1.w};
#pragma unroll
    for (int j = 0; j < 8; ++j) {
        unsigned b = __float_as_uint(f[j]);
        unsigned hb = b & 0xffff0000u;
        hi[j] = (short)(hb >> 16);
        float r = f[j] - __uint_as_float(hb);
        lo[j] = (short)(__float_as_uint(r) >> 16);
    }
}

__global__ __launch_bounds__(256) void k_gemm_bf16s(const float* __restrict__ A,
                                                    const float* __restrict__ Wt,
                                                    float* __restrict__ h,
                                                    unsigned short* __restrict__ hb,
                                                    int N, int M) {
    constexpr int K = 256;
    __shared__ float As[64][36];
    __shared__ float Bs[64][36];
    const int tid = threadIdx.x;
    const int lane = tid & 63;
    const int wid = tid >> 6;
    const int row0 = blockIdx.x * 64;
    const int col0 = blockIdx.y * 64;

    // staging mapping: 64 rows x 32 k, 8 floats per thread
    const int sr = tid >> 2;
    const int sk = (tid & 3) << 3;
    const int ga = row0 + sr;                 // A row (guarded)
    const size_t gaK = (size_t)ga * K;
    const size_t gcK = (size_t)(col0 + sr) * K;  // Wt row (always valid)

    // wave tile
    const int wr = (wid >> 1) * 32;
    const int wc = (wid & 1) * 32;
    const int fr = lane & 15;
    const int ko = (lane >> 4) * 8;

    f32x4 acc[2][2];
#pragma unroll
    for (int i = 0; i < 2; ++i)
#pragma unroll
        for (int j = 0; j < 2; ++j) acc[i][j] = (f32x4){0.f, 0.f, 0.f, 0.f};

    for (int k0 = 0; k0 < K; k0 += 32) {
        float4 a0 = {0.f, 0.f, 0.f, 0.f}, a1 = {0.f, 0.f, 0.f, 0.f};
        if (ga < N) {
            a0 = *reinterpret_cast<const float4*>(&A[gaK + k0 + sk]);
            a1 = *reinterpret_cast<const float4*>(&A[gaK + k0 + sk + 4]);
        }
        const float4 b0 = *reinterpret_cast<const float4*>(&Wt[gcK + k0 + sk]);
        const float4 b1 = *reinterpret_cast<const float4*>(&Wt[gcK + k0 + sk + 4]);
        *reinterpret_cast<float4*>(&As[sr][sk])     = a0;
        *reinterpret_cast<float4*>(&As[sr][sk + 4]) = a1;
        *reinterpret_cast<float4*>(&Bs[sr][sk])     = b0;
        *reinterpret_cast<float4*>(&Bs[sr][sk + 4]) = b1;
        __syncthreads();

        bf16x8 ahi[2], alo[2], bhi[2], blo[2];
#pragma unroll
        for (int i = 0; i < 2; ++i) {
            const float* p = &As[wr + i * 16 + fr][ko];
            cvt8(*reinterpret_cast<const float4*>(p),
                 *reinterpret_cast<const float4*>(p + 4), ahi[i], alo[i]);
        }
#pragma unroll
        for (int j = 0; j < 2; ++j) {
            const float* p = &Bs[wc + j * 16 + fr][ko];
            cvt8(*reinterpret_cast<const float4*>(p),
                 *reinterpret_cast<const float4*>(p + 4), bhi[j], blo[j]);
        }
#pragma unroll
        for (int i = 0; i < 2; ++i)
#pragma unroll
            for (int j = 0; j < 2; ++j) {
                acc[i][j] = __builtin_amdgcn_mfma_f32_16x16x32_bf16(ahi[i], bhi[j], acc[i][j], 0, 0, 0);
                acc[i][j] = __builtin_amdgcn_mfma_f32_16x16x32_bf16(ahi[i], blo[j], acc[i][j], 0, 0, 0);
                acc[i][j] = __builtin_amdgcn_mfma_f32_16x16x32_bf16(alo[i], bhi[j], acc[i][j], 0, 0, 0);
            }
        __syncthreads();
    }

    const int orow = (lane >> 4) * 4;
    const int ocol = lane & 15;
#pragma unroll
    for (int i = 0; i < 2; ++i) {
#pragma unroll
        for (int r = 0; r < 4; ++r) {
            const int row = row0 + wr + i * 16 + orow + r;
            if (row < N) {
#pragma unroll
                for (int j = 0; j < 2; ++j) {
                    const int col = col0 + wc + j * 16 + ocol;
                    const float v = acc[i][j][r];
                    h[(size_t)row * M + col] = v;
                    hb[(size_t)row * M + col] = f2bf_rne(v);
                }
            }
        }
    }
}

// ---------------- attention logits per node (fp32 h) ----------------
template <int HN, int CN, int VEC>
__global__ __launch_bounds__(256) void k_al2(const float* __restrict__ h,
                                             const float* __restrict__ asrc,
                                             const float* __restrict__ adst,
                                             float* __restrict__ als,
                                             float* __restrict__ ald, int N) {
    constexpr int HC = HN * CN;
    constexpr int LPH = CN / VEC;
    const int l = threadIdx.x & 63;
    const int n = blockIdx.x * 4 + (threadIdx.x >> 6);
    if (n >= N) return;
    const int ch = l * VEC;
    float ps, pd;
    if constexpr (VEC == 4) {
        const float4 hv = *reinterpret_cast<const float4*>(&h[(size_t)n * HC + ch]);
        const float4 av = *reinterpret_cast<const float4*>(&asrc[ch]);
        const float4 dv = *reinterpret_cast<const float4*>(&adst[ch]);
        ps = hv.x * av.x + hv.y * av.y + hv.z * av.z + hv.w * av.w;
        pd = hv.x * dv.x + hv.y * dv.y + hv.z * dv.z + hv.w * dv.w;
    } else {
        const float hv = h[(size_t)n * HC + ch];
        ps = hv * asrc[ch];
        pd = hv * adst[ch];
    }
#pragma unroll
    for (int o = 1; o < LPH; o <<= 1) { ps += __shfl_xor(ps, o); pd += __shfl_xor(pd, o); }
    if ((l % LPH) == 0) {
        const int hd = ch / CN;
        als[n * HN + hd] = ps;
        ald[n * HN + hd] = pd;
    }
}

// ---------------- per-node softmax + aggregate (bf16 h gather) ----------------
template <int HN, int CN, int VEC>
__global__ __launch_bounds__(256) void k_agg3(const unsigned short* __restrict__ hb,
                                              const float* __restrict__ als,
                                              const float* __restrict__ ald,
                                              const int* __restrict__ ptr,
                                              const int* __restrict__ srcs,
                                              const float* __restrict__ bias,
                                              float* __restrict__ out,
                                              int N, int relu) {
    constexpr int HC = HN * CN;
    constexpr int SUBS = 64 / HN;
    constexpr int CH = 64 / HN;
    const int l = threadIdx.x & 63;
    const int n = blockIdx.x * 4 + (threadIdx.x >> 6);
    if (n >= N) return;
    const int beg = ptr[n], end = ptr[n + 1];
    const int hd_e = l % HN;
    const int sub = l / HN;
    const float aldv = ald[n * HN + hd_e];

    // online softmax over incoming edges
    float m = -1e30f, ssum = 0.f;
    for (int j = beg + sub; j < end; j += SUBS) {
        const float e = leaky(als[srcs[j] * HN + hd_e] + aldv);
        if (e > m) { ssum = ssum * __expf(m - e) + 1.f; m = e; }
        else        ssum += __expf(e - m);
    }
#pragma unroll
    for (int o = HN; o < 64; o <<= 1) {
        const float m2 = __shfl_xor(m, o), s2 = __shfl_xor(ssum, o);
        const float mn = fmaxf(m, m2);
        ssum = ssum * __expf(m - mn) + s2 * __expf(m2 - mn);
        m = mn;
    }
    const float inv = 1.f / (ssum + 1e-16f);

    const int ch = l * VEC;
    const int hl = ch / CN;
    float acc[VEC];
#pragma unroll
    for (int v = 0; v < VEC; ++v) acc[v] = 0.f;

    for (int j0 = beg; j0 < end; j0 += CH) {
        const int j = j0 + sub;
        int sreg = 0;
        float alpha = 0.f;
        if (j < end) {
            sreg = srcs[j];
            const float e = leaky(als[sreg * HN + hd_e] + aldv);
            alpha = __expf(e - m) * inv;
        }
        const int cc = min(CH, end - j0);
        for (int c = 0; c < cc; ++c) {
            const int s   = __shfl(sreg, c * HN);
            const float a = __shfl(alpha, c * HN + hl);
            const unsigned short* hp = &hb[(size_t)s * HC + ch];
            if constexpr (VEC == 4) {
                const ushort4 hv = *reinterpret_cast<const ushort4*>(hp);
                acc[0] += a * bfu(hv.x); acc[1] += a * bfu(hv.y);
                acc[2] += a * bfu(hv.z); acc[3] += a * bfu(hv.w);
            } else {
                acc[0] += a * bfu(hp[0]);
            }
        }
    }

#pragma unroll
    for (int v = 0; v < VEC; ++v) {
        float o = acc[v] + bias[ch + v];
        if (relu) o = fmaxf(o, 0.f);
        acc[v] = o;
    }
    if constexpr (VEC == 4) {
        float4 vout;
        vout.x = acc[0]; vout.y = acc[1]; vout.z = acc[2]; vout.w = acc[3];
        *reinterpret_cast<float4*>(&out[(size_t)n * HC + ch]) = vout;
    } else {
        out[(size_t)n * HC + ch] = acc[0];
    }
}

// ---------------- launch ----------------

extern "C" void kernel_launch(void* const* d_in, const int* in_sizes, int n_in,
                              void* d_out, int out_size, void* d_ws, size_t ws_size,
                              hipStream_t stream) {
    const float* x   = (const float*)d_in[0];
    const int*   ei  = (const int*)d_in[1];
    const float* W1  = (const float*)d_in[2];
    const float* as1 = (const float*)d_in[3];
    const float* ad1 = (const float*)d_in[4];
    const float* b1  = (const float*)d_in[5];
    const float* W2  = (const float*)d_in[6];
    const float* as2 = (const float*)d_in[7];
    const float* ad2 = (const float*)d_in[8];
    const float* b2  = (const float*)d_in[9];
    const float* W3  = (const float*)d_in[10];
    const float* as3 = (const float*)d_in[11];
    const float* ad3 = (const float*)d_in[12];
    const float* b3  = (const float*)d_in[13];

    const int F  = 256;
    const int N  = in_sizes[0] / F;     // 50000
    const int E  = in_sizes[1] / 2;     // 800000
    const int Et = E + N;

    char* w = (char*)d_ws;
    auto alloc = [&](size_t bytes) {
        char* p = w;
        w += (bytes + 255) & ~(size_t)255;
        return p;
    };
    float*          bufG = (float*)alloc((size_t)N * F * 4);           // h fp32
    unsigned short* hB   = (unsigned short*)alloc((size_t)N * F * 2);  // h bf16
    float*          bufA = (float*)alloc((size_t)N * F * 4);           // layer out
    float* Wt1 = (float*)alloc((size_t)256 * 256 * 4);
    float* Wt2 = (float*)alloc((size_t)256 * 256 * 4);
    float* Wt3 = (float*)alloc((size_t)64 * 256 * 4);
    float* als  = (float*)alloc((size_t)N * 8 * 4);
    float* ald  = (float*)alloc((size_t)N * 8 * 4);
    int*   cnt  = (int*)alloc((size_t)N * 4);
    int*   ptr  = (int*)alloc((size_t)(N + 1) * 4);
    int*   fptr = (int*)alloc((size_t)(N + 1) * 4);
    int*   srcs = (int*)alloc((size_t)Et * 4);
    int*   bsum = (int*)alloc(4096);

    // ---- CSR build (by dst) ----
    const int nb = (N + 1023) / 1024;
    hipLaunchKernelGGL(k_set1,      dim3((N + 255) / 256),  dim3(256), 0, stream, cnt, N);
    hipLaunchKernelGGL(k_count,     dim3((E + 255) / 256),  dim3(256), 0, stream, ei + E, cnt, E);
    hipLaunchKernelGGL(k_scan_local,dim3(nb),               dim3(256), 0, stream, cnt, ptr, bsum, N);
    hipLaunchKernelGGL(k_scan_bsums,dim3(1),                dim3(64),  0, stream, bsum, nb);
    hipLaunchKernelGGL(k_scan_add,  dim3((N + 256) / 256),  dim3(256), 0, stream, ptr, bsum, N, Et);
    hipLaunchKernelGGL(k_copy,      dim3((N + 255) / 256),  dim3(256), 0, stream, fptr, ptr, N);
    hipLaunchKernelGGL(k_fillcsr,   dim3((Et + 255) / 256), dim3(256), 0, stream, ei, fptr, srcs, E, Et);

    // ---- W transposes ----
    hipLaunchKernelGGL(k_transpose, dim3(256 / 32, 256 / 32), dim3(256), 0, stream, W1, Wt1, 256, 256);
    hipLaunchKernelGGL(k_transpose, dim3(256 / 32, 256 / 32), dim3(256), 0, stream, W2, Wt2, 256, 256);
    hipLaunchKernelGGL(k_transpose, dim3(64 / 32, 256 / 32),  dim3(256), 0, stream, W3, Wt3, 256, 64);

    const dim3 gN4((N + 3) / 4);
    const int gx = (N + 63) / 64;

    // ---- layer 1 ----
    hipLaunchKernelGGL(k_gemm_bf16s, dim3(gx, 4), dim3(256), 0, stream, x, Wt1, bufG, hB, N, 256);
    hipLaunchKernelGGL((k_al2<8, 32, 4>), gN4, dim3(256), 0, stream, bufG, as1, ad1, als, ald, N);
    hipLaunchKernelGGL((k_agg3<8, 32, 4>), gN4, dim3(256), 0, stream, hB, als, ald, ptr, srcs, b1, bufA, N, 1);
    // ---- layer 2 ----
    hipLaunchKernelGGL(k_gemm_bf16s, dim3(gx, 4), dim3(256), 0, stream, bufA, Wt2, bufG, hB, N, 256);
    hipLaunchKernelGGL((k_al2<8, 32, 4>), gN4, dim3(256), 0, stream, bufG, as2, ad2, als, ald, N);
    hipLaunchKernelGGL((k_agg3<8, 32, 4>), gN4, dim3(256), 0, stream, hB, als, ald, ptr, srcs, b2, bufA, N, 1);
    // ---- layer 3 ----
    hipLaunchKernelGGL(k_gemm_bf16s, dim3(gx, 1), dim3(256), 0, stream, bufA, Wt3, bufG, hB, N, 64);
    hipLaunchKernelGGL((k_al2<1, 64, 1>), gN4, dim3(256), 0, stream, bufG, as3, ad3, als, ald, N);
    hipLaunchKernelGGL((k_agg3<1, 64, 1>), gN4, dim3(256), 0, stream, hB, als, ald, ptr, srcs, b3, (float*)d_out, N, 0);
}

// Round 7
// 448.163 us; speedup vs baseline: 2.1543x; 1.1147x over previous
//
#include <hip/hip_runtime.h>
#include <math.h>

#define NSLOPE 0.2f

typedef __attribute__((ext_vector_type(8))) short bf16x8;
typedef __attribute__((ext_vector_type(4))) float f32x4;

static __device__ __forceinline__ float leaky(float e) {
    return e > 0.f ? e : NSLOPE * e;
}

static __device__ __forceinline__ float bfu(unsigned short u) {
    return __uint_as_float(((unsigned)u) << 16);
}

static __device__ __forceinline__ unsigned short f2bf_rne(float f) {
    unsigned b = __float_as_uint(f);
    unsigned r = b + 0x7fffu + ((b >> 16) & 1u);
    return (unsigned short)(r >> 16);
}

// ---------------- CSR build (round-3 verbatim) ----------------

__global__ void k_set1(int* __restrict__ c, int N) {
    int i = blockIdx.x * blockDim.x + threadIdx.x;
    if (i < N) c[i] = 1;
}

__global__ void k_count(const int* __restrict__ dst, int* __restrict__ cnt, int E) {
    int i = blockIdx.x * blockDim.x + threadIdx.x;
    if (i < E) atomicAdd(&cnt[dst[i]], 1);
}

__global__ void k_scan_local(const int* __restrict__ cnt, int* __restrict__ ptr,
                             int* __restrict__ bsum, int N) {
    __shared__ int sd[256];
    int t = threadIdx.x;
    int i0 = blockIdx.x * 1024 + t * 4;
    int v0 = (i0 + 0 < N) ? cnt[i0 + 0] : 0;
    int v1 = (i0 + 1 < N) ? cnt[i0 + 1] : 0;
    int v2 = (i0 + 2 < N) ? cnt[i0 + 2] : 0;
    int v3 = (i0 + 3 < N) ? cnt[i0 + 3] : 0;
    int ts = v0 + v1 + v2 + v3;
    sd[t] = ts;
    __syncthreads();
    for (int o = 1; o < 256; o <<= 1) {
        int add = (t >= o) ? sd[t - o] : 0;
        __syncthreads();
        sd[t] += add;
        __syncthreads();
    }
    int run = sd[t] - ts;
    if (i0 + 0 < N) ptr[i0 + 0] = run; run += v0;
    if (i0 + 1 < N) ptr[i0 + 1] = run; run += v1;
    if (i0 + 2 < N) ptr[i0 + 2] = run; run += v2;
    if (i0 + 3 < N) ptr[i0 + 3] = run;
    if (t == 255) bsum[blockIdx.x] = sd[255];
}

__global__ void k_scan_bsums(int* __restrict__ bsum, int nb) {
    if (threadIdx.x == 0 && blockIdx.x == 0) {
        int run = 0;
        for (int b = 0; b < nb; ++b) { int t = bsum[b]; bsum[b] = run; run += t; }
    }
}

__global__ void k_scan_add(int* __restrict__ ptr, const int* __restrict__ bsum,
                           int N, int Et) {
    int i = blockIdx.x * blockDim.x + threadIdx.x;
    if (i < N) ptr[i] += bsum[i >> 10];
    else if (i == N) ptr[N] = Et;
}

__global__ void k_copy(int* __restrict__ d, const int* __restrict__ s, int N) {
    int i = blockIdx.x * blockDim.x + threadIdx.x;
    if (i < N) d[i] = s[i];
}

__global__ void k_fillcsr(const int* __restrict__ ei, int* __restrict__ fptr,
                          int* __restrict__ srcs, int E, int Et) {
    int i = blockIdx.x * blockDim.x + threadIdx.x;
    if (i >= Et) return;
    int s, d;
    if (i < E) { s = ei[i]; d = ei[E + i]; }
    else       { s = d = i - E; }
    int pos = atomicAdd(&fptr[d], 1);
    srcs[pos] = s;
}

// ---------------- W transpose: Wt[M][K] = W[K][M] ----------------
__global__ __launch_bounds__(256) void k_transpose(const float* __restrict__ B,
                                                   float* __restrict__ Bt,
                                                   int K, int M) {
    __shared__ float tile[32][33];
    const int bx = blockIdx.x * 32;
    const int by = blockIdx.y * 32;
    const int tx = threadIdx.x & 31, ty = threadIdx.x >> 5;
    for (int r = ty; r < 32; r += 8) tile[r][tx] = B[(size_t)(by + r) * M + bx + tx];
    __syncthreads();
    for (int r = ty; r < 32; r += 8) Bt[(size_t)(bx + r) * K + by + tx] = tile[tx][r];
}

// ---------------- split-bf16 MFMA GEMM (round-3 verbatim, passing) ----------

static __device__ __forceinline__ void cvt8(float4 v0, float4 v1,
                                            bf16x8& hi, bf16x8& lo) {
    float f[8] = {v0.x, v0.y, v0.z, v0.w, v1.x, v1.y, v1.z, v1.w};
#pragma unroll
    for (int j = 0; j < 8; ++j) {
        unsigned b = __float_as_uint(f[j]);
        unsigned hb = b & 0xffff0000u;
        hi[j] = (short)(hb >> 16);
        float r = f[j] - __uint_as_float(hb);
        lo[j] = (short)(__float_as_uint(r) >> 16);
    }
}

__global__ __launch_bounds__(256) void k_gemm_bf16s(const float* __restrict__ A,
                                                    const float* __restrict__ Wt,
                                                    float* __restrict__ h,
                                                    unsigned short* __restrict__ hb,
                                                    int N, int M) {
    constexpr int K = 256;
    __shared__ float As[64][36];
    __shared__ float Bs[64][36];
    const int tid = threadIdx.x;
    const int lane = tid & 63;
    const int wid = tid >> 6;
    const int row0 = blockIdx.x * 64;
    const int col0 = blockIdx.y * 64;

    const int sr = tid >> 2;
    const int sk = (tid & 3) << 3;
    const int ga = row0 + sr;
    const size_t gaK = (size_t)ga * K;
    const size_t gcK = (size_t)(col0 + sr) * K;

    const int wr = (wid >> 1) * 32;
    const int wc = (wid & 1) * 32;
    const int fr = lane & 15;
    const int ko = (lane >> 4) * 8;

    f32x4 acc[2][2];
#pragma unroll
    for (int i = 0; i < 2; ++i)
#pragma unroll
        for (int j = 0; j < 2; ++j) acc[i][j] = (f32x4){0.f, 0.f, 0.f, 0.f};

    for (int k0 = 0; k0 < K; k0 += 32) {
        float4 a0 = {0.f, 0.f, 0.f, 0.f}, a1 = {0.f, 0.f, 0.f, 0.f};
        if (ga < N) {
            a0 = *reinterpret_cast<const float4*>(&A[gaK + k0 + sk]);
            a1 = *reinterpret_cast<const float4*>(&A[gaK + k0 + sk + 4]);
        }
        const float4 b0 = *reinterpret_cast<const float4*>(&Wt[gcK + k0 + sk]);
        const float4 b1 = *reinterpret_cast<const float4*>(&Wt[gcK + k0 + sk + 4]);
        *reinterpret_cast<float4*>(&As[sr][sk])     = a0;
        *reinterpret_cast<float4*>(&As[sr][sk + 4]) = a1;
        *reinterpret_cast<float4*>(&Bs[sr][sk])     = b0;
        *reinterpret_cast<float4*>(&Bs[sr][sk + 4]) = b1;
        __syncthreads();

        bf16x8 ahi[2], alo[2], bhi[2], blo[2];
#pragma unroll
        for (int i = 0; i < 2; ++i) {
            const float* p = &As[wr + i * 16 + fr][ko];
            cvt8(*reinterpret_cast<const float4*>(p),
                 *reinterpret_cast<const float4*>(p + 4), ahi[i], alo[i]);
        }
#pragma unroll
        for (int j = 0; j < 2; ++j) {
            const float* p = &Bs[wc + j * 16 + fr][ko];
            cvt8(*reinterpret_cast<const float4*>(p),
                 *reinterpret_cast<const float4*>(p + 4), bhi[j], blo[j]);
        }
#pragma unroll
        for (int i = 0; i < 2; ++i)
#pragma unroll
            for (int j = 0; j < 2; ++j) {
                acc[i][j] = __builtin_amdgcn_mfma_f32_16x16x32_bf16(ahi[i], bhi[j], acc[i][j], 0, 0, 0);
                acc[i][j] = __builtin_amdgcn_mfma_f32_16x16x32_bf16(ahi[i], blo[j], acc[i][j], 0, 0, 0);
                acc[i][j] = __builtin_amdgcn_mfma_f32_16x16x32_bf16(alo[i], bhi[j], acc[i][j], 0, 0, 0);
            }
        __syncthreads();
    }

    const int orow = (lane >> 4) * 4;
    const int ocol = lane & 15;
#pragma unroll
    for (int i = 0; i < 2; ++i) {
#pragma unroll
        for (int r = 0; r < 4; ++r) {
            const int row = row0 + wr + i * 16 + orow + r;
            if (row < N) {
#pragma unroll
                for (int j = 0; j < 2; ++j) {
                    const int col = col0 + wc + j * 16 + ocol;
                    const float v = acc[i][j][r];
                    h[(size_t)row * M + col] = v;
                    hb[(size_t)row * M + col] = f2bf_rne(v);
                }
            }
        }
    }
}

// ---------------- attention logits per node (round-3 verbatim) --------------
template <int HN, int CN, int VEC>
__global__ __launch_bounds__(256) void k_al2(const float* __restrict__ h,
                                             const float* __restrict__ asrc,
                                             const float* __restrict__ adst,
                                             float* __restrict__ als,
                                             float* __restrict__ ald, int N) {
    constexpr int HC = HN * CN;
    constexpr int LPH = CN / VEC;
    const int l = threadIdx.x & 63;
    const int n = blockIdx.x * 4 + (threadIdx.x >> 6);
    if (n >= N) return;
    const int ch = l * VEC;
    float ps, pd;
    if constexpr (VEC == 4) {
        const float4 hv = *reinterpret_cast<const float4*>(&h[(size_t)n * HC + ch]);
        const float4 av = *reinterpret_cast<const float4*>(&asrc[ch]);
        const float4 dv = *reinterpret_cast<const float4*>(&adst[ch]);
        ps = hv.x * av.x + hv.y * av.y + hv.z * av.z + hv.w * av.w;
        pd = hv.x * dv.x + hv.y * dv.y + hv.z * dv.z + hv.w * dv.w;
    } else {
        const float hv = h[(size_t)n * HC + ch];
        ps = hv * asrc[ch];
        pd = hv * adst[ch];
    }
#pragma unroll
    for (int o = 1; o < LPH; o <<= 1) { ps += __shfl_xor(ps, o); pd += __shfl_xor(pd, o); }
    if ((l % LPH) == 0) {
        const int hd = ch / CN;
        als[n * HN + hd] = ps;
        ald[n * HN + hd] = pd;
    }
}

// ---------------- per-node softmax + aggregate ----------------
// Round-3 k_agg3 structure verbatim; ONLY change: inner c-loop processes
// gathers in batches of GB=8 (loads first, FMAs after) for memory-level
// parallelism, with the original scalar loop as the tail path.
template <int HN, int CN, int VEC>
__global__ __launch_bounds__(256) void k_agg5(const unsigned short* __restrict__ hb,
                                              const float* __restrict__ als,
                                              const float* __restrict__ ald,
                                              const int* __restrict__ ptr,
                                              const int* __restrict__ srcs,
                                              const float* __restrict__ bias,
                                              float* __restrict__ out,
                                              int N, int relu) {
    constexpr int HC = HN * CN;
    constexpr int SUBS = 64 / HN;
    constexpr int CH = 64 / HN;
    constexpr int GB = (CH < 8) ? CH : 8;
    const int l = threadIdx.x & 63;
    const int n = blockIdx.x * 4 + (threadIdx.x >> 6);
    if (n >= N) return;
    const int beg = ptr[n], end = ptr[n + 1];
    const int hd_e = l % HN;
    const int sub = l / HN;
    const float aldv = ald[n * HN + hd_e];

    // online softmax over incoming edges (round-3 verbatim)
    float m = -1e30f, ssum = 0.f;
    for (int j = beg + sub; j < end; j += SUBS) {
        const float e = leaky(als[srcs[j] * HN + hd_e] + aldv);
        if (e > m) { ssum = ssum * __expf(m - e) + 1.f; m = e; }
        else        ssum += __expf(e - m);
    }
#pragma unroll
    for (int o = HN; o < 64; o <<= 1) {
        const float m2 = __shfl_xor(m, o), s2 = __shfl_xor(ssum, o);
        const float mn = fmaxf(m, m2);
        ssum = ssum * __expf(m - mn) + s2 * __expf(m2 - mn);
        m = mn;
    }
    const float inv = 1.f / (ssum + 1e-16f);

    const int ch = l * VEC;
    const int hl = ch / CN;
    float acc[VEC];
#pragma unroll
    for (int v = 0; v < VEC; ++v) acc[v] = 0.f;

    for (int j0 = beg; j0 < end; j0 += CH) {
        const int j = j0 + sub;
        int sreg = 0;
        float alpha = 0.f;
        if (j < end) {
            sreg = srcs[j];
            const float e = leaky(als[sreg * HN + hd_e] + aldv);
            alpha = __expf(e - m) * inv;
        }
        const int cc = min(CH, end - j0);
        int c = 0;
        // batched-gather fast path: GB loads in flight, then FMAs
        for (; c + GB <= cc; c += GB) {
            float av[GB];
            if constexpr (VEC == 4) {
                ushort4 hv[GB];
#pragma unroll
                for (int k = 0; k < GB; ++k) {
                    const int s = __shfl(sreg, (c + k) * HN);
                    av[k] = __shfl(alpha, (c + k) * HN + hl);
                    hv[k] = *reinterpret_cast<const ushort4*>(&hb[(size_t)s * HC + ch]);
                }
#pragma unroll
                for (int k = 0; k < GB; ++k) {
                    acc[0] += av[k] * bfu(hv[k].x);
                    acc[1] += av[k] * bfu(hv[k].y);
                    acc[2] += av[k] * bfu(hv[k].z);
                    acc[3] += av[k] * bfu(hv[k].w);
                }
            } else {
                unsigned short hv[GB];
#pragma unroll
                for (int k = 0; k < GB; ++k) {
                    const int s = __shfl(sreg, (c + k) * HN);
                    av[k] = __shfl(alpha, (c + k) * HN + hl);
                    hv[k] = hb[(size_t)s * HC + ch];
                }
#pragma unroll
                for (int k = 0; k < GB; ++k) acc[0] += av[k] * bfu(hv[k]);
            }
        }
        // scalar tail (round-3 verbatim)
        for (; c < cc; ++c) {
            const int s = __shfl(sreg, c * HN);
            const float a = __shfl(alpha, c * HN + hl);
            if constexpr (VEC == 4) {
                const ushort4 hv = *reinterpret_cast<const ushort4*>(&hb[(size_t)s * HC + ch]);
                acc[0] += a * bfu(hv.x);
                acc[1] += a * bfu(hv.y);
                acc[2] += a * bfu(hv.z);
                acc[3] += a * bfu(hv.w);
            } else {
                acc[0] += a * bfu(hb[(size_t)s * HC + ch]);
            }
        }
    }

#pragma unroll
    for (int v = 0; v < VEC; ++v) {
        float o = acc[v] + bias[ch + v];
        if (relu) o = fmaxf(o, 0.f);
        acc[v] = o;
    }
    if constexpr (VEC == 4) {
        float4 vout;
        vout.x = acc[0]; vout.y = acc[1]; vout.z = acc[2]; vout.w = acc[3];
        *reinterpret_cast<float4*>(&out[(size_t)n * HC + ch]) = vout;
    } else {
        out[(size_t)n * HC + ch] = acc[0];
    }
}

// ---------------- launch ----------------

extern "C" void kernel_launch(void* const* d_in, const int* in_sizes, int n_in,
                              void* d_out, int out_size, void* d_ws, size_t ws_size,
                              hipStream_t stream) {
    const float* x   = (const float*)d_in[0];
    const int*   ei  = (const int*)d_in[1];
    const float* W1  = (const float*)d_in[2];
    const float* as1 = (const float*)d_in[3];
    const float* ad1 = (const float*)d_in[4];
    const float* b1  = (const float*)d_in[5];
    const float* W2  = (const float*)d_in[6];
    const float* as2 = (const float*)d_in[7];
    const float* ad2 = (const float*)d_in[8];
    const float* b2  = (const float*)d_in[9];
    const float* W3  = (const float*)d_in[10];
    const float* as3 = (const float*)d_in[11];
    const float* ad3 = (const float*)d_in[12];
    const float* b3  = (const float*)d_in[13];

    const int F  = 256;
    const int N  = in_sizes[0] / F;     // 50000
    const int E  = in_sizes[1] / 2;     // 800000
    const int Et = E + N;

    char* w = (char*)d_ws;
    auto alloc = [&](size_t bytes) {
        char* p = w;
        w += (bytes + 255) & ~(size_t)255;
        return p;
    };
    float*          bufG = (float*)alloc((size_t)N * F * 4);           // h fp32
    unsigned short* hB   = (unsigned short*)alloc((size_t)N * F * 2);  // h bf16
    float*          bufA = (float*)alloc((size_t)N * F * 4);           // layer out
    float* Wt1 = (float*)alloc((size_t)256 * 256 * 4);
    float* Wt2 = (float*)alloc((size_t)256 * 256 * 4);
    float* Wt3 = (float*)alloc((size_t)64 * 256 * 4);
    float* als  = (float*)alloc((size_t)N * 8 * 4);
    float* ald  = (float*)alloc((size_t)N * 8 * 4);
    int*   cnt  = (int*)alloc((size_t)N * 4);
    int*   ptr  = (int*)alloc((size_t)(N + 1) * 4);
    int*   fptr = (int*)alloc((size_t)(N + 1) * 4);
    int*   srcs = (int*)alloc((size_t)Et * 4);
    int*   bsum = (int*)alloc(4096);

    // ---- CSR build (by dst), round-3 verbatim ----
    const int nb = (N + 1023) / 1024;
    hipLaunchKernelGGL(k_set1,      dim3((N + 255) / 256),  dim3(256), 0, stream, cnt, N);
    hipLaunchKernelGGL(k_count,     dim3((E + 255) / 256),  dim3(256), 0, stream, ei + E, cnt, E);
    hipLaunchKernelGGL(k_scan_local,dim3(nb),               dim3(256), 0, stream, cnt, ptr, bsum, N);
    hipLaunchKernelGGL(k_scan_bsums,dim3(1),                dim3(64),  0, stream, bsum, nb);
    hipLaunchKernelGGL(k_scan_add,  dim3((N + 256) / 256),  dim3(256), 0, stream, ptr, bsum, N, Et);
    hipLaunchKernelGGL(k_copy,      dim3((N + 255) / 256),  dim3(256), 0, stream, fptr, ptr, N);
    hipLaunchKernelGGL(k_fillcsr,   dim3((Et + 255) / 256), dim3(256), 0, stream, ei, fptr, srcs, E, Et);

    // ---- W transposes ----
    hipLaunchKernelGGL(k_transpose, dim3(8, 8), dim3(256), 0, stream, W1, Wt1, 256, 256);
    hipLaunchKernelGGL(k_transpose, dim3(8, 8), dim3(256), 0, stream, W2, Wt2, 256, 256);
    hipLaunchKernelGGL(k_transpose, dim3(2, 8), dim3(256), 0, stream, W3, Wt3, 256, 64);

    const dim3 gN4((N + 3) / 4);
    const int gx = (N + 63) / 64;

    // ---- layer 1 ----
    hipLaunchKernelGGL(k_gemm_bf16s, dim3(gx, 4), dim3(256), 0, stream, x, Wt1, bufG, hB, N, 256);
    hipLaunchKernelGGL((k_al2<8, 32, 4>), gN4, dim3(256), 0, stream, bufG, as1, ad1, als, ald, N);
    hipLaunchKernelGGL((k_agg5<8, 32, 4>), gN4, dim3(256), 0, stream,
                       hB, als, ald, ptr, srcs, b1, bufA, N, 1);
    // ---- layer 2 ----
    hipLaunchKernelGGL(k_gemm_bf16s, dim3(gx, 4), dim3(256), 0, stream, bufA, Wt2, bufG, hB, N, 256);
    hipLaunchKernelGGL((k_al2<8, 32, 4>), gN4, dim3(256), 0, stream, bufG, as2, ad2, als, ald, N);
    hipLaunchKernelGGL((k_agg5<8, 32, 4>), gN4, dim3(256), 0, stream,
                       hB, als, ald, ptr, srcs, b2, bufA, N, 1);
    // ---- layer 3 ----
    hipLaunchKernelGGL(k_gemm_bf16s, dim3(gx, 1), dim3(256), 0, stream, bufA, Wt3, bufG, hB, N, 64);
    hipLaunchKernelGGL((k_al2<1, 64, 1>), gN4, dim3(256), 0, stream, bufG, as3, ad3, als, ald, N);
    hipLaunchKernelGGL((k_agg5<1, 64, 1>), gN4, dim3(256), 0, stream,
                       hB, als, ald, ptr, srcs, b3, (float*)d_out, N, 0);
}

// Round 8
// 439.791 us; speedup vs baseline: 2.1953x; 1.0190x over previous
//
#include <hip/hip_runtime.h>
#include <math.h>

#define NSLOPE 0.2f

typedef __attribute__((ext_vector_type(8))) short bf16x8;
typedef __attribute__((ext_vector_type(8))) unsigned short ushort8;
typedef __attribute__((ext_vector_type(4))) float f32x4;

static __device__ __forceinline__ float leaky(float e) {
    return e > 0.f ? e : NSLOPE * e;
}

static __device__ __forceinline__ float bfu(unsigned short u) {
    return __uint_as_float(((unsigned)u) << 16);
}

static __device__ __forceinline__ unsigned short f2bf_rne(float f) {
    unsigned b = __float_as_uint(f);
    unsigned r = b + 0x7fffu + ((b >> 16) & 1u);
    return (unsigned short)(r >> 16);
}

// split fp32 -> hi (truncate) + lo (truncate of residual); identical math to
// the old in-GEMM cvt8, so MFMA inputs are bit-identical.
static __device__ __forceinline__ void split1(float f, unsigned short& hi,
                                              unsigned short& lo) {
    unsigned b = __float_as_uint(f);
    unsigned hb = b & 0xffff0000u;
    hi = (unsigned short)(hb >> 16);
    lo = (unsigned short)(__float_as_uint(f - __uint_as_float(hb)) >> 16);
}

// ---------------- CSR build (round-3 verbatim) ----------------

__global__ void k_set1(int* __restrict__ c, int N) {
    int i = blockIdx.x * blockDim.x + threadIdx.x;
    if (i < N) c[i] = 1;
}

__global__ void k_count(const int* __restrict__ dst, int* __restrict__ cnt, int E) {
    int i = blockIdx.x * blockDim.x + threadIdx.x;
    if (i < E) atomicAdd(&cnt[dst[i]], 1);
}

__global__ void k_scan_local(const int* __restrict__ cnt, int* __restrict__ ptr,
                             int* __restrict__ bsum, int N) {
    __shared__ int sd[256];
    int t = threadIdx.x;
    int i0 = blockIdx.x * 1024 + t * 4;
    int v0 = (i0 + 0 < N) ? cnt[i0 + 0] : 0;
    int v1 = (i0 + 1 < N) ? cnt[i0 + 1] : 0;
    int v2 = (i0 + 2 < N) ? cnt[i0 + 2] : 0;
    int v3 = (i0 + 3 < N) ? cnt[i0 + 3] : 0;
    int ts = v0 + v1 + v2 + v3;
    sd[t] = ts;
    __syncthreads();
    for (int o = 1; o < 256; o <<= 1) {
        int add = (t >= o) ? sd[t - o] : 0;
        __syncthreads();
        sd[t] += add;
        __syncthreads();
    }
    int run = sd[t] - ts;
    if (i0 + 0 < N) ptr[i0 + 0] = run; run += v0;
    if (i0 + 1 < N) ptr[i0 + 1] = run; run += v1;
    if (i0 + 2 < N) ptr[i0 + 2] = run; run += v2;
    if (i0 + 3 < N) ptr[i0 + 3] = run;
    if (t == 255) bsum[blockIdx.x] = sd[255];
}

__global__ void k_scan_bsums(int* __restrict__ bsum, int nb) {
    if (threadIdx.x == 0 && blockIdx.x == 0) {
        int run = 0;
        for (int b = 0; b < nb; ++b) { int t = bsum[b]; bsum[b] = run; run += t; }
    }
}

__global__ void k_scan_add(int* __restrict__ ptr, const int* __restrict__ bsum,
                           int N, int Et) {
    int i = blockIdx.x * blockDim.x + threadIdx.x;
    if (i < N) ptr[i] += bsum[i >> 10];
    else if (i == N) ptr[N] = Et;
}

__global__ void k_copy(int* __restrict__ d, const int* __restrict__ s, int N) {
    int i = blockIdx.x * blockDim.x + threadIdx.x;
    if (i < N) d[i] = s[i];
}

__global__ void k_fillcsr(const int* __restrict__ ei, int* __restrict__ fptr,
                          int* __restrict__ srcs, int E, int Et) {
    int i = blockIdx.x * blockDim.x + threadIdx.x;
    if (i >= Et) return;
    int s, d;
    if (i < E) { s = ei[i]; d = ei[E + i]; }
    else       { s = d = i - E; }
    int pos = atomicAdd(&fptr[d], 1);
    srcs[pos] = s;
}

// ---------------- input split: fp32 -> hi/lo bf16 ----------------
__global__ void k_split(const float* __restrict__ in, unsigned short* __restrict__ hi,
                        unsigned short* __restrict__ lo, int n8) {
    int i = blockIdx.x * blockDim.x + threadIdx.x;
    if (i >= n8) return;
    const float4 v0 = *reinterpret_cast<const float4*>(&in[(size_t)i * 8]);
    const float4 v1 = *reinterpret_cast<const float4*>(&in[(size_t)i * 8 + 4]);
    const float f[8] = {v0.x, v0.y, v0.z, v0.w, v1.x, v1.y, v1.z, v1.w};
    ushort8 h, l;
#pragma unroll
    for (int j = 0; j < 8; ++j) {
        unsigned short hj, lj;
        split1(f[j], hj, lj);
        h[j] = hj; l[j] = lj;
    }
    *reinterpret_cast<ushort8*>(&hi[(size_t)i * 8]) = h;
    *reinterpret_cast<ushort8*>(&lo[(size_t)i * 8]) = l;
}

// ---------------- W transpose + split: Wt{hi,lo}[M][K] = split(W[K][M]) -----
__global__ __launch_bounds__(256) void k_transposeS(const float* __restrict__ B,
                                                    unsigned short* __restrict__ Bthi,
                                                    unsigned short* __restrict__ Btlo,
                                                    int K, int M) {
    __shared__ float tile[32][33];
    const int bx = blockIdx.x * 32;   // M offset
    const int by = blockIdx.y * 32;   // K offset
    const int tx = threadIdx.x & 31, ty = threadIdx.x >> 5;
    for (int r = ty; r < 32; r += 8) tile[r][tx] = B[(size_t)(by + r) * M + bx + tx];
    __syncthreads();
    for (int r = ty; r < 32; r += 8) {
        unsigned short h, l;
        split1(tile[tx][r], h, l);
        Bthi[(size_t)(bx + r) * K + by + tx] = h;
        Btlo[(size_t)(bx + r) * K + by + tx] = l;
    }
}

// ---------------- split-bf16 MFMA GEMM, pre-split inputs, fused logits ------
// C[N,M] = A[N,256] @ W; A,Wt given as hi/lo bf16. M = HN*CN.
// Writes hb (bf16 RNE of C) and als/ald per-node per-head logits.

template <int HN, int CN>
__global__ __launch_bounds__(256) void k_gemm_s(const unsigned short* __restrict__ Ahi,
                                                const unsigned short* __restrict__ Alo,
                                                const unsigned short* __restrict__ Whi,
                                                const unsigned short* __restrict__ Wlo,
                                                const float* __restrict__ asrc,
                                                const float* __restrict__ adst,
                                                unsigned short* __restrict__ hb,
                                                float* __restrict__ als,
                                                float* __restrict__ ald,
                                                int N) {
    constexpr int K = 256;
    constexpr int M = HN * CN;
    __shared__ unsigned short Ah[64][40], Al[64][40], Bh[64][40], Bl[64][40];
    const int tid = threadIdx.x;
    const int lane = tid & 63;
    const int wid = tid >> 6;
    const int row0 = blockIdx.x * 64;
    const int col0 = blockIdx.y * 64;

    const int sr = tid >> 2;
    const int sk = (tid & 3) << 3;
    const int ga = row0 + sr;
    const size_t gaK = (size_t)ga * K;
    const size_t gcK = (size_t)(col0 + sr) * K;

    const int wr = (wid >> 1) * 32;
    const int wc = (wid & 1) * 32;
    const int fr = lane & 15;
    const int ko = (lane >> 4) * 8;

    f32x4 acc[2][2];
#pragma unroll
    for (int i = 0; i < 2; ++i)
#pragma unroll
        for (int j = 0; j < 2; ++j) acc[i][j] = (f32x4){0.f, 0.f, 0.f, 0.f};

    for (int k0 = 0; k0 < K; k0 += 32) {
        ushort8 ah = {0,0,0,0,0,0,0,0}, al = {0,0,0,0,0,0,0,0};
        if (ga < N) {
            ah = *reinterpret_cast<const ushort8*>(&Ahi[gaK + k0 + sk]);
            al = *reinterpret_cast<const ushort8*>(&Alo[gaK + k0 + sk]);
        }
        const ushort8 bh = *reinterpret_cast<const ushort8*>(&Whi[gcK + k0 + sk]);
        const ushort8 bl = *reinterpret_cast<const ushort8*>(&Wlo[gcK + k0 + sk]);
        *reinterpret_cast<ushort8*>(&Ah[sr][sk]) = ah;
        *reinterpret_cast<ushort8*>(&Al[sr][sk]) = al;
        *reinterpret_cast<ushort8*>(&Bh[sr][sk]) = bh;
        *reinterpret_cast<ushort8*>(&Bl[sr][sk]) = bl;
        __syncthreads();

        bf16x8 ahi[2], alo[2], bhi[2], blo[2];
#pragma unroll
        for (int i = 0; i < 2; ++i) {
            ahi[i] = *reinterpret_cast<const bf16x8*>(&Ah[wr + i * 16 + fr][ko]);
            alo[i] = *reinterpret_cast<const bf16x8*>(&Al[wr + i * 16 + fr][ko]);
        }
#pragma unroll
        for (int j = 0; j < 2; ++j) {
            bhi[j] = *reinterpret_cast<const bf16x8*>(&Bh[wc + j * 16 + fr][ko]);
            blo[j] = *reinterpret_cast<const bf16x8*>(&Bl[wc + j * 16 + fr][ko]);
        }
#pragma unroll
        for (int i = 0; i < 2; ++i)
#pragma unroll
            for (int j = 0; j < 2; ++j) {
                acc[i][j] = __builtin_amdgcn_mfma_f32_16x16x32_bf16(ahi[i], bhi[j], acc[i][j], 0, 0, 0);
                acc[i][j] = __builtin_amdgcn_mfma_f32_16x16x32_bf16(ahi[i], blo[j], acc[i][j], 0, 0, 0);
                acc[i][j] = __builtin_amdgcn_mfma_f32_16x16x32_bf16(alo[i], bhi[j], acc[i][j], 0, 0, 0);
            }
        __syncthreads();
    }

    const int orow = (lane >> 4) * 4;
    const int ocol = lane & 15;

    // ---- hb (bf16) store ----
#pragma unroll
    for (int i = 0; i < 2; ++i) {
#pragma unroll
        for (int r = 0; r < 4; ++r) {
            const int row = row0 + wr + i * 16 + orow + r;
            if (row < N) {
#pragma unroll
                for (int j = 0; j < 2; ++j) {
                    const int col = col0 + wc + j * 16 + ocol;
                    hb[(size_t)row * M + col] = f2bf_rne(acc[i][j][r]);
                }
            }
        }
    }

    // ---- fused attention logits (exonerated by r5/r6 bit-identity) ----
    const int c0 = col0 + wc;
    const float as0 = asrc[c0 + ocol],      as1 = asrc[c0 + 16 + ocol];
    const float ad0 = adst[c0 + ocol],      ad1 = adst[c0 + 16 + ocol];

    if constexpr (CN == 32) {
        const int head = c0 >> 5;
#pragma unroll
        for (int i = 0; i < 2; ++i) {
#pragma unroll
            for (int r = 0; r < 4; ++r) {
                float ps = acc[i][0][r] * as0 + acc[i][1][r] * as1;
                float pd = acc[i][0][r] * ad0 + acc[i][1][r] * ad1;
#pragma unroll
                for (int o = 1; o < 16; o <<= 1) {
                    ps += __shfl_xor(ps, o);
                    pd += __shfl_xor(pd, o);
                }
                const int row = row0 + wr + i * 16 + orow + r;
                if (ocol == 0 && row < N) {
                    als[(size_t)row * HN + head] = ps;
                    ald[(size_t)row * HN + head] = pd;
                }
            }
        }
    } else {
        // CN == 64, HN == 1: head spans both wave-column halves -> LDS combine
        __shared__ float part[2][64][2];
#pragma unroll
        for (int i = 0; i < 2; ++i) {
#pragma unroll
            for (int r = 0; r < 4; ++r) {
                float ps = acc[i][0][r] * as0 + acc[i][1][r] * as1;
                float pd = acc[i][0][r] * ad0 + acc[i][1][r] * ad1;
#pragma unroll
                for (int o = 1; o < 16; o <<= 1) {
                    ps += __shfl_xor(ps, o);
                    pd += __shfl_xor(pd, o);
                }
                if (ocol == 0) {
                    const int lr = wr + i * 16 + orow + r;
                    part[wc >> 5][lr][0] = ps;
                    part[wc >> 5][lr][1] = pd;
                }
            }
        }
        __syncthreads();
        if (tid < 64) {
            const int row = row0 + tid;
            if (row < N) {
                als[row] = part[0][tid][0] + part[1][tid][0];
                ald[row] = part[0][tid][1] + part[1][tid][1];
            }
        }
    }
}

// ---------------- per-node softmax + aggregate (r7 verbatim + OSPLIT out) ---
template <int HN, int CN, int VEC, bool OSPLIT>
__global__ __launch_bounds__(256) void k_agg5(const unsigned short* __restrict__ hb,
                                              const float* __restrict__ als,
                                              const float* __restrict__ ald,
                                              const int* __restrict__ ptr,
                                              const int* __restrict__ srcs,
                                              const float* __restrict__ bias,
                                              unsigned short* __restrict__ ohi,
                                              unsigned short* __restrict__ olo,
                                              float* __restrict__ out,
                                              int N, int relu) {
    constexpr int HC = HN * CN;
    constexpr int SUBS = 64 / HN;
    constexpr int CH = 64 / HN;
    constexpr int GB = (CH < 8) ? CH : 8;
    const int l = threadIdx.x & 63;
    const int n = blockIdx.x * 4 + (threadIdx.x >> 6);
    if (n >= N) return;
    const int beg = ptr[n], end = ptr[n + 1];
    const int hd_e = l % HN;
    const int sub = l / HN;
    const float aldv = ald[n * HN + hd_e];

    // online softmax over incoming edges
    float m = -1e30f, ssum = 0.f;
    for (int j = beg + sub; j < end; j += SUBS) {
        const float e = leaky(als[srcs[j] * HN + hd_e] + aldv);
        if (e > m) { ssum = ssum * __expf(m - e) + 1.f; m = e; }
        else        ssum += __expf(e - m);
    }
#pragma unroll
    for (int o = HN; o < 64; o <<= 1) {
        const float m2 = __shfl_xor(m, o), s2 = __shfl_xor(ssum, o);
        const float mn = fmaxf(m, m2);
        ssum = ssum * __expf(m - mn) + s2 * __expf(m2 - mn);
        m = mn;
    }
    const float inv = 1.f / (ssum + 1e-16f);

    const int ch = l * VEC;
    const int hl = ch / CN;
    float acc[VEC];
#pragma unroll
    for (int v = 0; v < VEC; ++v) acc[v] = 0.f;

    for (int j0 = beg; j0 < end; j0 += CH) {
        const int j = j0 + sub;
        int sreg = 0;
        float alpha = 0.f;
        if (j < end) {
            sreg = srcs[j];
            const float e = leaky(als[sreg * HN + hd_e] + aldv);
            alpha = __expf(e - m) * inv;
        }
        const int cc = min(CH, end - j0);
        int c = 0;
        for (; c + GB <= cc; c += GB) {
            float av[GB];
            if constexpr (VEC == 4) {
                ushort4 hv[GB];
#pragma unroll
                for (int k = 0; k < GB; ++k) {
                    const int s = __shfl(sreg, (c + k) * HN);
                    av[k] = __shfl(alpha, (c + k) * HN + hl);
                    hv[k] = *reinterpret_cast<const ushort4*>(&hb[(size_t)s * HC + ch]);
                }
#pragma unroll
                for (int k = 0; k < GB; ++k) {
                    acc[0] += av[k] * bfu(hv[k].x);
                    acc[1] += av[k] * bfu(hv[k].y);
                    acc[2] += av[k] * bfu(hv[k].z);
                    acc[3] += av[k] * bfu(hv[k].w);
                }
            } else {
                unsigned short hv[GB];
#pragma unroll
                for (int k = 0; k < GB; ++k) {
                    const int s = __shfl(sreg, (c + k) * HN);
                    av[k] = __shfl(alpha, (c + k) * HN + hl);
                    hv[k] = hb[(size_t)s * HC + ch];
                }
#pragma unroll
                for (int k = 0; k < GB; ++k) acc[0] += av[k] * bfu(hv[k]);
            }
        }
        for (; c < cc; ++c) {
            const int s = __shfl(sreg, c * HN);
            const float a = __shfl(alpha, c * HN + hl);
            if constexpr (VEC == 4) {
                const ushort4 hv = *reinterpret_cast<const ushort4*>(&hb[(size_t)s * HC + ch]);
                acc[0] += a * bfu(hv.x);
                acc[1] += a * bfu(hv.y);
                acc[2] += a * bfu(hv.z);
                acc[3] += a * bfu(hv.w);
            } else {
                acc[0] += a * bfu(hb[(size_t)s * HC + ch]);
            }
        }
    }

#pragma unroll
    for (int v = 0; v < VEC; ++v) {
        float o = acc[v] + bias[ch + v];
        if (relu) o = fmaxf(o, 0.f);
        acc[v] = o;
    }
    if constexpr (OSPLIT) {
        // write split hi/lo bf16 (same truncation as split1) for next GEMM
        ushort4 ho, lo4;
        unsigned short h0, l0;
        split1(acc[0], h0, l0); ho.x = h0; lo4.x = l0;
        split1(acc[1], h0, l0); ho.y = h0; lo4.y = l0;
        split1(acc[2], h0, l0); ho.z = h0; lo4.z = l0;
        split1(acc[3], h0, l0); ho.w = h0; lo4.w = l0;
        *reinterpret_cast<ushort4*>(&ohi[(size_t)n * HC + ch]) = ho;
        *reinterpret_cast<ushort4*>(&olo[(size_t)n * HC + ch]) = lo4;
    } else if constexpr (VEC == 4) {
        float4 vout;
        vout.x = acc[0]; vout.y = acc[1]; vout.z = acc[2]; vout.w = acc[3];
        *reinterpret_cast<float4*>(&out[(size_t)n * HC + ch]) = vout;
    } else {
        out[(size_t)n * HC + ch] = acc[0];
    }
}

// ---------------- launch ----------------

extern "C" void kernel_launch(void* const* d_in, const int* in_sizes, int n_in,
                              void* d_out, int out_size, void* d_ws, size_t ws_size,
                              hipStream_t stream) {
    const float* x   = (const float*)d_in[0];
    const int*   ei  = (const int*)d_in[1];
    const float* W1  = (const float*)d_in[2];
    const float* as1 = (const float*)d_in[3];
    const float* ad1 = (const float*)d_in[4];
    const float* b1  = (const float*)d_in[5];
    const float* W2  = (const float*)d_in[6];
    const float* as2 = (const float*)d_in[7];
    const float* ad2 = (const float*)d_in[8];
    const float* b2  = (const float*)d_in[9];
    const float* W3  = (const float*)d_in[10];
    const float* as3 = (const float*)d_in[11];
    const float* ad3 = (const float*)d_in[12];
    const float* b3  = (const float*)d_in[13];

    const int F  = 256;
    const int N  = in_sizes[0] / F;     // 50000
    const int E  = in_sizes[1] / 2;     // 800000
    const int Et = E + N;

    char* w = (char*)d_ws;
    auto alloc = [&](size_t bytes) {
        char* p = w;
        w += (bytes + 255) & ~(size_t)255;
        return p;
    };
    // S0: x split (reused later only as scratch); S1: agg output split (L1 & L2)
    unsigned short* S0hi = (unsigned short*)alloc((size_t)N * F * 2);
    unsigned short* S0lo = (unsigned short*)alloc((size_t)N * F * 2);
    unsigned short* S1hi = (unsigned short*)alloc((size_t)N * F * 2);
    unsigned short* S1lo = (unsigned short*)alloc((size_t)N * F * 2);
    unsigned short* hB   = (unsigned short*)alloc((size_t)N * F * 2);  // gemm out bf16
    unsigned short* Wt1hi = (unsigned short*)alloc((size_t)256 * 256 * 2);
    unsigned short* Wt1lo = (unsigned short*)alloc((size_t)256 * 256 * 2);
    unsigned short* Wt2hi = (unsigned short*)alloc((size_t)256 * 256 * 2);
    unsigned short* Wt2lo = (unsigned short*)alloc((size_t)256 * 256 * 2);
    unsigned short* Wt3hi = (unsigned short*)alloc((size_t)64 * 256 * 2);
    unsigned short* Wt3lo = (unsigned short*)alloc((size_t)64 * 256 * 2);
    float* als  = (float*)alloc((size_t)N * 8 * 4);
    float* ald  = (float*)alloc((size_t)N * 8 * 4);
    int*   cnt  = (int*)alloc((size_t)N * 4);
    int*   ptr  = (int*)alloc((size_t)(N + 1) * 4);
    int*   fptr = (int*)alloc((size_t)(N + 1) * 4);
    int*   srcs = (int*)alloc((size_t)Et * 4);
    int*   bsum = (int*)alloc(4096);

    // ---- CSR build (by dst), round-3 verbatim ----
    const int nb = (N + 1023) / 1024;
    hipLaunchKernelGGL(k_set1,      dim3((N + 255) / 256),  dim3(256), 0, stream, cnt, N);
    hipLaunchKernelGGL(k_count,     dim3((E + 255) / 256),  dim3(256), 0, stream, ei + E, cnt, E);
    hipLaunchKernelGGL(k_scan_local,dim3(nb),               dim3(256), 0, stream, cnt, ptr, bsum, N);
    hipLaunchKernelGGL(k_scan_bsums,dim3(1),                dim3(64),  0, stream, bsum, nb);
    hipLaunchKernelGGL(k_scan_add,  dim3((N + 256) / 256),  dim3(256), 0, stream, ptr, bsum, N, Et);
    hipLaunchKernelGGL(k_copy,      dim3((N + 255) / 256),  dim3(256), 0, stream, fptr, ptr, N);
    hipLaunchKernelGGL(k_fillcsr,   dim3((Et + 255) / 256), dim3(256), 0, stream, ei, fptr, srcs, E, Et);

    // ---- weight transpose+split, input split ----
    hipLaunchKernelGGL(k_transposeS, dim3(8, 8), dim3(256), 0, stream, W1, Wt1hi, Wt1lo, 256, 256);
    hipLaunchKernelGGL(k_transposeS, dim3(8, 8), dim3(256), 0, stream, W2, Wt2hi, Wt2lo, 256, 256);
    hipLaunchKernelGGL(k_transposeS, dim3(2, 8), dim3(256), 0, stream, W3, Wt3hi, Wt3lo, 256, 64);
    const int n8 = N * F / 8;
    hipLaunchKernelGGL(k_split, dim3((n8 + 255) / 256), dim3(256), 0, stream, x, S0hi, S0lo, n8);

    const dim3 gN4((N + 3) / 4);
    const int gx = (N + 63) / 64;

    // ---- layer 1 ----
    hipLaunchKernelGGL((k_gemm_s<8, 32>), dim3(gx, 4), dim3(256), 0, stream,
                       S0hi, S0lo, Wt1hi, Wt1lo, as1, ad1, hB, als, ald, N);
    hipLaunchKernelGGL((k_agg5<8, 32, 4, true>), gN4, dim3(256), 0, stream,
                       hB, als, ald, ptr, srcs, b1, S1hi, S1lo, nullptr, N, 1);
    // ---- layer 2 ---- (agg output overwrites S1 in-place is unsafe; gemm2
    // reads S1 before agg2 runs, so agg2 may write S1 again: stream-ordered.)
    hipLaunchKernelGGL((k_gemm_s<8, 32>), dim3(gx, 4), dim3(256), 0, stream,
                       S1hi, S1lo, Wt2hi, Wt2lo, as2, ad2, hB, als, ald, N);
    hipLaunchKernelGGL((k_agg5<8, 32, 4, true>), gN4, dim3(256), 0, stream,
                       hB, als, ald, ptr, srcs, b2, S0hi, S0lo, nullptr, N, 1);
    // ---- layer 3 ----
    hipLaunchKernelGGL((k_gemm_s<1, 64>), dim3(gx, 1), dim3(256), 0, stream,
                       S0hi, S0lo, Wt3hi, Wt3lo, as3, ad3, hB, als, ald, N);
    hipLaunchKernelGGL((k_agg5<1, 64, 1, false>), gN4, dim3(256), 0, stream,
                       hB, als, ald, ptr, srcs, b3, nullptr, nullptr, (float*)d_out, N, 0);
}

// Round 9
// 412.882 us; speedup vs baseline: 2.3384x; 1.0652x over previous
//
#include <hip/hip_runtime.h>
#include <math.h>

#define NSLOPE 0.2f

typedef __attribute__((ext_vector_type(8))) short bf16x8;
typedef __attribute__((ext_vector_type(8))) unsigned short ushort8;
typedef __attribute__((ext_vector_type(4))) float f32x4;

static __device__ __forceinline__ float leaky(float e) {
    return e > 0.f ? e : NSLOPE * e;
}

static __device__ __forceinline__ float bfu(unsigned short u) {
    return __uint_as_float(((unsigned)u) << 16);
}

static __device__ __forceinline__ unsigned short f2bf_rne(float f) {
    unsigned b = __float_as_uint(f);
    unsigned r = b + 0x7fffu + ((b >> 16) & 1u);
    return (unsigned short)(r >> 16);
}

static __device__ __forceinline__ void split1(float f, unsigned short& hi,
                                              unsigned short& lo) {
    unsigned b = __float_as_uint(f);
    unsigned hb = b & 0xffff0000u;
    hi = (unsigned short)(hb >> 16);
    lo = (unsigned short)(__float_as_uint(f - __uint_as_float(hb)) >> 16);
}

// ---------------- CSR build ----------------

__global__ void k_count(const int* __restrict__ dst, int* __restrict__ cnt, int E) {
    int i = blockIdx.x * blockDim.x + threadIdx.x;
    if (i < E) atomicAdd(&cnt[dst[i]], 1);
}

__global__ void k_scan_local(const int* __restrict__ cnt, int* __restrict__ ptr,
                             int* __restrict__ bsum, int N) {
    __shared__ int sd[256];
    int t = threadIdx.x;
    int i0 = blockIdx.x * 1024 + t * 4;
    int v0 = (i0 + 0 < N) ? cnt[i0 + 0] : 0;
    int v1 = (i0 + 1 < N) ? cnt[i0 + 1] : 0;
    int v2 = (i0 + 2 < N) ? cnt[i0 + 2] : 0;
    int v3 = (i0 + 3 < N) ? cnt[i0 + 3] : 0;
    int ts = v0 + v1 + v2 + v3;
    sd[t] = ts;
    __syncthreads();
    for (int o = 1; o < 256; o <<= 1) {
        int add = (t >= o) ? sd[t - o] : 0;
        __syncthreads();
        sd[t] += add;
        __syncthreads();
    }
    int run = sd[t] - ts;
    if (i0 + 0 < N) ptr[i0 + 0] = run; run += v0;
    if (i0 + 1 < N) ptr[i0 + 1] = run; run += v1;
    if (i0 + 2 < N) ptr[i0 + 2] = run; run += v2;
    if (i0 + 3 < N) ptr[i0 + 3] = run;
    if (t == 255) bsum[blockIdx.x] = sd[255];
}

// folds the serial bsum scan into per-block prefix (chunk = 1024 elems = 4 blocks)
__global__ void k_scan_add2(int* __restrict__ ptr, const int* __restrict__ bsum,
                            int N, int Et) {
    __shared__ int base;
    const int chunk = blockIdx.x >> 2;
    if (threadIdx.x == 0) {
        int s = 0;
        for (int b = 0; b < chunk; ++b) s += bsum[b];
        base = s;
    }
    __syncthreads();
    int i = blockIdx.x * 256 + threadIdx.x;
    if (i < N) ptr[i] += base;
    else if (i == N) ptr[N] = Et;
}

__global__ void k_copy(int* __restrict__ d, const int* __restrict__ s, int N) {
    int i = blockIdx.x * blockDim.x + threadIdx.x;
    if (i < N) d[i] = s[i];
}

__global__ void k_fillcsr(const int* __restrict__ ei, int* __restrict__ fptr,
                          int* __restrict__ srcs, int E, int Et) {
    int i = blockIdx.x * blockDim.x + threadIdx.x;
    if (i >= Et) return;
    int s, d;
    if (i < E) { s = ei[i]; d = ei[E + i]; }
    else       { s = d = i - E; }
    int pos = atomicAdd(&fptr[d], 1);
    srcs[pos] = s;
}

// ---------------- fused prep: cnt=1  ||  x split  ||  3x W transpose+split ---
__global__ __launch_bounds__(256) void k_prep(
    int* __restrict__ cnt, int N,
    const float* __restrict__ x, unsigned short* __restrict__ xhi,
    unsigned short* __restrict__ xlo, int n8,
    const float* __restrict__ W1, unsigned short* __restrict__ w1h, unsigned short* __restrict__ w1l,
    const float* __restrict__ W2, unsigned short* __restrict__ w2h, unsigned short* __restrict__ w2l,
    const float* __restrict__ W3, unsigned short* __restrict__ w3h, unsigned short* __restrict__ w3l,
    int nset, int nsplit) {
    __shared__ float tile[32][33];
    const int b = blockIdx.x;
    const int tid = threadIdx.x;
    if (b < nset) {
        int i = b * 256 + tid;
        if (i < N) cnt[i] = 1;
    } else if (b < nset + nsplit) {
        int i = (b - nset) * 256 + tid;
        if (i < n8) {
            const float4 v0 = *reinterpret_cast<const float4*>(&x[(size_t)i * 8]);
            const float4 v1 = *reinterpret_cast<const float4*>(&x[(size_t)i * 8 + 4]);
            const float f[8] = {v0.x, v0.y, v0.z, v0.w, v1.x, v1.y, v1.z, v1.w};
            ushort8 h, l;
#pragma unroll
            for (int j = 0; j < 8; ++j) {
                unsigned short hj, lj;
                split1(f[j], hj, lj);
                h[j] = hj; l[j] = lj;
            }
            *reinterpret_cast<ushort8*>(&xhi[(size_t)i * 8]) = h;
            *reinterpret_cast<ushort8*>(&xlo[(size_t)i * 8]) = l;
        }
    } else {
        int tb = b - nset - nsplit;     // 0..143
        const float* B; unsigned short *H, *L;
        int M, bx, by;
        if (tb < 64)       { B = W1; H = w1h; L = w1l; M = 256; bx = (tb & 7) * 32; by = (tb >> 3) * 32; }
        else if (tb < 128) { tb -= 64;  B = W2; H = w2h; L = w2l; M = 256; bx = (tb & 7) * 32; by = (tb >> 3) * 32; }
        else               { tb -= 128; B = W3; H = w3h; L = w3l; M = 64;  bx = (tb & 1) * 32; by = (tb >> 1) * 32; }
        constexpr int K = 256;
        const int tx = tid & 31, ty = tid >> 5;
        for (int r = ty; r < 32; r += 8) tile[r][tx] = B[(size_t)(by + r) * M + bx + tx];
        __syncthreads();
        for (int r = ty; r < 32; r += 8) {
            unsigned short h, l;
            split1(tile[tx][r], h, l);
            H[(size_t)(bx + r) * K + by + tx] = h;
            L[(size_t)(bx + r) * K + by + tx] = l;
        }
    }
}

// ---------------- split-bf16 MFMA GEMM, pre-split inputs, fused logits ------

template <int HN, int CN>
__global__ __launch_bounds__(256) void k_gemm_s(const unsigned short* __restrict__ Ahi,
                                                const unsigned short* __restrict__ Alo,
                                                const unsigned short* __restrict__ Whi,
                                                const unsigned short* __restrict__ Wlo,
                                                const float* __restrict__ asrc,
                                                const float* __restrict__ adst,
                                                unsigned short* __restrict__ hb,
                                                float* __restrict__ als,
                                                float* __restrict__ ald,
                                                int N) {
    constexpr int K = 256;
    constexpr int M = HN * CN;
    __shared__ unsigned short Ah[64][40], Al[64][40], Bh[64][40], Bl[64][40];
    const int tid = threadIdx.x;
    const int lane = tid & 63;
    const int wid = tid >> 6;
    const int row0 = blockIdx.x * 64;
    const int col0 = blockIdx.y * 64;

    const int sr = tid >> 2;
    const int sk = (tid & 3) << 3;
    const int ga = row0 + sr;
    const size_t gaK = (size_t)ga * K;
    const size_t gcK = (size_t)(col0 + sr) * K;

    const int wr = (wid >> 1) * 32;
    const int wc = (wid & 1) * 32;
    const int fr = lane & 15;
    const int ko = (lane >> 4) * 8;

    f32x4 acc[2][2];
#pragma unroll
    for (int i = 0; i < 2; ++i)
#pragma unroll
        for (int j = 0; j < 2; ++j) acc[i][j] = (f32x4){0.f, 0.f, 0.f, 0.f};

    for (int k0 = 0; k0 < K; k0 += 32) {
        ushort8 ah = {0,0,0,0,0,0,0,0}, al = {0,0,0,0,0,0,0,0};
        if (ga < N) {
            ah = *reinterpret_cast<const ushort8*>(&Ahi[gaK + k0 + sk]);
            al = *reinterpret_cast<const ushort8*>(&Alo[gaK + k0 + sk]);
        }
        const ushort8 bh = *reinterpret_cast<const ushort8*>(&Whi[gcK + k0 + sk]);
        const ushort8 bl = *reinterpret_cast<const ushort8*>(&Wlo[gcK + k0 + sk]);
        *reinterpret_cast<ushort8*>(&Ah[sr][sk]) = ah;
        *reinterpret_cast<ushort8*>(&Al[sr][sk]) = al;
        *reinterpret_cast<ushort8*>(&Bh[sr][sk]) = bh;
        *reinterpret_cast<ushort8*>(&Bl[sr][sk]) = bl;
        __syncthreads();

        bf16x8 ahi[2], alo[2], bhi[2], blo[2];
#pragma unroll
        for (int i = 0; i < 2; ++i) {
            ahi[i] = *reinterpret_cast<const bf16x8*>(&Ah[wr + i * 16 + fr][ko]);
            alo[i] = *reinterpret_cast<const bf16x8*>(&Al[wr + i * 16 + fr][ko]);
        }
#pragma unroll
        for (int j = 0; j < 2; ++j) {
            bhi[j] = *reinterpret_cast<const bf16x8*>(&Bh[wc + j * 16 + fr][ko]);
            blo[j] = *reinterpret_cast<const bf16x8*>(&Bl[wc + j * 16 + fr][ko]);
        }
#pragma unroll
        for (int i = 0; i < 2; ++i)
#pragma unroll
            for (int j = 0; j < 2; ++j) {
                acc[i][j] = __builtin_amdgcn_mfma_f32_16x16x32_bf16(ahi[i], bhi[j], acc[i][j], 0, 0, 0);
                acc[i][j] = __builtin_amdgcn_mfma_f32_16x16x32_bf16(ahi[i], blo[j], acc[i][j], 0, 0, 0);
                acc[i][j] = __builtin_amdgcn_mfma_f32_16x16x32_bf16(alo[i], bhi[j], acc[i][j], 0, 0, 0);
            }
        __syncthreads();
    }

    const int orow = (lane >> 4) * 4;
    const int ocol = lane & 15;

#pragma unroll
    for (int i = 0; i < 2; ++i) {
#pragma unroll
        for (int r = 0; r < 4; ++r) {
            const int row = row0 + wr + i * 16 + orow + r;
            if (row < N) {
#pragma unroll
                for (int j = 0; j < 2; ++j) {
                    const int col = col0 + wc + j * 16 + ocol;
                    hb[(size_t)row * M + col] = f2bf_rne(acc[i][j][r]);
                }
            }
        }
    }

    const int c0 = col0 + wc;
    const float as0 = asrc[c0 + ocol],      as1 = asrc[c0 + 16 + ocol];
    const float ad0 = adst[c0 + ocol],      ad1 = adst[c0 + 16 + ocol];

    if constexpr (CN == 32) {
        const int head = c0 >> 5;
#pragma unroll
        for (int i = 0; i < 2; ++i) {
#pragma unroll
            for (int r = 0; r < 4; ++r) {
                float ps = acc[i][0][r] * as0 + acc[i][1][r] * as1;
                float pd = acc[i][0][r] * ad0 + acc[i][1][r] * ad1;
#pragma unroll
                for (int o = 1; o < 16; o <<= 1) {
                    ps += __shfl_xor(ps, o);
                    pd += __shfl_xor(pd, o);
                }
                const int row = row0 + wr + i * 16 + orow + r;
                if (ocol == 0 && row < N) {
                    als[(size_t)row * HN + head] = ps;
                    ald[(size_t)row * HN + head] = pd;
                }
            }
        }
    } else {
        __shared__ float part[2][64][2];
#pragma unroll
        for (int i = 0; i < 2; ++i) {
#pragma unroll
            for (int r = 0; r < 4; ++r) {
                float ps = acc[i][0][r] * as0 + acc[i][1][r] * as1;
                float pd = acc[i][0][r] * ad0 + acc[i][1][r] * ad1;
#pragma unroll
                for (int o = 1; o < 16; o <<= 1) {
                    ps += __shfl_xor(ps, o);
                    pd += __shfl_xor(pd, o);
                }
                if (ocol == 0) {
                    const int lr = wr + i * 16 + orow + r;
                    part[wc >> 5][lr][0] = ps;
                    part[wc >> 5][lr][1] = pd;
                }
            }
        }
        __syncthreads();
        if (tid < 64) {
            const int row = row0 + tid;
            if (row < N) {
                als[row] = part[0][tid][0] + part[1][tid][0];
                ald[row] = part[0][tid][1] + part[1][tid][1];
            }
        }
    }
}

// ---------------- per-node softmax + aggregate, register-stashed alphas -----
// Pass 1 keeps srcs + p=exp(leaky(logit)) for the first P*SUBS edges in regs
// (no max subtraction: logits are O(5), exp is fp32-safe). Pass 2 is pure
// shfl+gather+FMA with no loads/exp on the critical path. Overflow edges
// (degree > P*SUBS, vanishingly rare) recompute alphas.
template <int HN, int CN, int VEC, int P, bool OSPLIT>
__global__ __launch_bounds__(256) void k_agg6(const unsigned short* __restrict__ hb,
                                              const float* __restrict__ als,
                                              const float* __restrict__ ald,
                                              const int* __restrict__ ptr,
                                              const int* __restrict__ srcs,
                                              const float* __restrict__ bias,
                                              unsigned short* __restrict__ ohi,
                                              unsigned short* __restrict__ olo,
                                              float* __restrict__ out,
                                              int N, int relu) {
    constexpr int HC = HN * CN;
    constexpr int SUBS = 64 / HN;              // edges per batch
    constexpr int GB = (SUBS < 16) ? SUBS : 16; // gathers in flight per sub-batch
    const int l = threadIdx.x & 63;
    const int n = blockIdx.x * 4 + (threadIdx.x >> 6);
    if (n >= N) return;
    const int beg = ptr[n], end = ptr[n + 1];
    const int hd_e = l % HN;
    const int sub = l / HN;
    const float aldv = ald[(unsigned)n * HN + hd_e];

    // ---- pass 1: exp-sum + register stash ----
    float p[P];
    int   sr[P];
    float ssum = 0.f;
#pragma unroll
    for (int b = 0; b < P; ++b) {
        const int j = beg + b * SUBS + sub;
        float pv = 0.f; int s = 0;
        if (j < end) {
            s = srcs[j];
            pv = __expf(leaky(als[(unsigned)s * HN + hd_e] + aldv));
        }
        sr[b] = s; p[b] = pv; ssum += pv;
    }
    for (int j = beg + P * SUBS + sub; j < end; j += SUBS) {
        ssum += __expf(leaky(als[(unsigned)srcs[j] * HN + hd_e] + aldv));
    }
#pragma unroll
    for (int o = HN; o < 64; o <<= 1) ssum += __shfl_xor(ssum, o);
    const float inv = 1.f / (ssum + 1e-16f);

    // ---- pass 2: aggregation ----
    const int ch = l * VEC;
    const int hl = ch / CN;
    float acc[VEC];
#pragma unroll
    for (int v = 0; v < VEC; ++v) acc[v] = 0.f;

#pragma unroll
    for (int b = 0; b < P; ++b) {
        const int j0 = beg + b * SUBS;
        if (j0 >= end) break;
        const float am = p[b] * inv;   // alpha for this lane's (head, edge)
#pragma unroll
        for (int cb = 0; cb < SUBS / GB; ++cb) {
            if (j0 + cb * GB >= end) break;
            float av[GB];
            if constexpr (VEC == 4) {
                ushort4 hv[GB];
#pragma unroll
                for (int c = 0; c < GB; ++c) {
                    const int ce = cb * GB + c;
                    const int s = __shfl(sr[b], ce * HN);
                    av[c] = __shfl(am, ce * HN + hl);
                    hv[c] = *reinterpret_cast<const ushort4*>(&hb[(unsigned)s * HC + ch]);
                }
#pragma unroll
                for (int c = 0; c < GB; ++c) {
                    acc[0] += av[c] * bfu(hv[c].x);
                    acc[1] += av[c] * bfu(hv[c].y);
                    acc[2] += av[c] * bfu(hv[c].z);
                    acc[3] += av[c] * bfu(hv[c].w);
                }
            } else {
                unsigned short hv[GB];
#pragma unroll
                for (int c = 0; c < GB; ++c) {
                    const int ce = cb * GB + c;
                    const int s = __shfl(sr[b], ce * HN);
                    av[c] = __shfl(am, ce * HN + hl);
                    hv[c] = hb[(unsigned)s * HC + ch];
                }
#pragma unroll
                for (int c = 0; c < GB; ++c) acc[0] += av[c] * bfu(hv[c]);
            }
        }
    }
    // overflow edges (degree > P*SUBS): recompute alpha
    for (int j0 = beg + P * SUBS; j0 < end; j0 += SUBS) {
        const int j = j0 + sub;
        int sm = 0; float am = 0.f;
        if (j < end) {
            sm = srcs[j];
            am = __expf(leaky(als[(unsigned)sm * HN + hd_e] + aldv)) * inv;
        }
#pragma unroll
        for (int cb = 0; cb < SUBS / GB; ++cb) {
            if (j0 + cb * GB >= end) break;
            float av[GB];
            if constexpr (VEC == 4) {
                ushort4 hv[GB];
#pragma unroll
                for (int c = 0; c < GB; ++c) {
                    const int ce = cb * GB + c;
                    const int s = __shfl(sm, ce * HN);
                    av[c] = __shfl(am, ce * HN + hl);
                    hv[c] = *reinterpret_cast<const ushort4*>(&hb[(unsigned)s * HC + ch]);
                }
#pragma unroll
                for (int c = 0; c < GB; ++c) {
                    acc[0] += av[c] * bfu(hv[c].x);
                    acc[1] += av[c] * bfu(hv[c].y);
                    acc[2] += av[c] * bfu(hv[c].z);
                    acc[3] += av[c] * bfu(hv[c].w);
                }
            } else {
                unsigned short hv[GB];
#pragma unroll
                for (int c = 0; c < GB; ++c) {
                    const int ce = cb * GB + c;
                    const int s = __shfl(sm, ce * HN);
                    av[c] = __shfl(am, ce * HN + hl);
                    hv[c] = hb[(unsigned)s * HC + ch];
                }
#pragma unroll
                for (int c = 0; c < GB; ++c) acc[0] += av[c] * bfu(hv[c]);
            }
        }
    }

#pragma unroll
    for (int v = 0; v < VEC; ++v) {
        float o = acc[v] + bias[ch + v];
        if (relu) o = fmaxf(o, 0.f);
        acc[v] = o;
    }
    if constexpr (OSPLIT) {
        ushort4 ho, lo4;
        unsigned short h0, l0;
        split1(acc[0], h0, l0); ho.x = h0; lo4.x = l0;
        split1(acc[1], h0, l0); ho.y = h0; lo4.y = l0;
        split1(acc[2], h0, l0); ho.z = h0; lo4.z = l0;
        split1(acc[3], h0, l0); ho.w = h0; lo4.w = l0;
        *reinterpret_cast<ushort4*>(&ohi[(unsigned)n * HC + ch]) = ho;
        *reinterpret_cast<ushort4*>(&olo[(unsigned)n * HC + ch]) = lo4;
    } else if constexpr (VEC == 4) {
        float4 vout;
        vout.x = acc[0]; vout.y = acc[1]; vout.z = acc[2]; vout.w = acc[3];
        *reinterpret_cast<float4*>(&out[(unsigned)n * HC + ch]) = vout;
    } else {
        out[(unsigned)n * HC + ch] = acc[0];
    }
}

// ---------------- launch ----------------

extern "C" void kernel_launch(void* const* d_in, const int* in_sizes, int n_in,
                              void* d_out, int out_size, void* d_ws, size_t ws_size,
                              hipStream_t stream) {
    const float* x   = (const float*)d_in[0];
    const int*   ei  = (const int*)d_in[1];
    const float* W1  = (const float*)d_in[2];
    const float* as1 = (const float*)d_in[3];
    const float* ad1 = (const float*)d_in[4];
    const float* b1  = (const float*)d_in[5];
    const float* W2  = (const float*)d_in[6];
    const float* as2 = (const float*)d_in[7];
    const float* ad2 = (const float*)d_in[8];
    const float* b2  = (const float*)d_in[9];
    const float* W3  = (const float*)d_in[10];
    const float* as3 = (const float*)d_in[11];
    const float* ad3 = (const float*)d_in[12];
    const float* b3  = (const float*)d_in[13];

    const int F  = 256;
    const int N  = in_sizes[0] / F;     // 50000
    const int E  = in_sizes[1] / 2;     // 800000
    const int Et = E + N;

    char* w = (char*)d_ws;
    auto alloc = [&](size_t bytes) {
        char* p = w;
        w += (bytes + 255) & ~(size_t)255;
        return p;
    };
    unsigned short* S0hi = (unsigned short*)alloc((size_t)N * F * 2);
    unsigned short* S0lo = (unsigned short*)alloc((size_t)N * F * 2);
    unsigned short* S1hi = (unsigned short*)alloc((size_t)N * F * 2);
    unsigned short* S1lo = (unsigned short*)alloc((size_t)N * F * 2);
    unsigned short* hB   = (unsigned short*)alloc((size_t)N * F * 2);
    unsigned short* Wt1hi = (unsigned short*)alloc((size_t)256 * 256 * 2);
    unsigned short* Wt1lo = (unsigned short*)alloc((size_t)256 * 256 * 2);
    unsigned short* Wt2hi = (unsigned short*)alloc((size_t)256 * 256 * 2);
    unsigned short* Wt2lo = (unsigned short*)alloc((size_t)256 * 256 * 2);
    unsigned short* Wt3hi = (unsigned short*)alloc((size_t)64 * 256 * 2);
    unsigned short* Wt3lo = (unsigned short*)alloc((size_t)64 * 256 * 2);
    float* als  = (float*)alloc((size_t)N * 8 * 4);
    float* ald  = (float*)alloc((size_t)N * 8 * 4);
    int*   cnt  = (int*)alloc((size_t)N * 4);
    int*   ptr  = (int*)alloc((size_t)(N + 1) * 4);
    int*   fptr = (int*)alloc((size_t)(N + 1) * 4);
    int*   srcs = (int*)alloc((size_t)Et * 4);
    int*   bsum = (int*)alloc(4096);

    const int n8 = N * F / 8;
    const int nset = (N + 255) / 256;
    const int nsplit = (n8 + 255) / 256;
    const int nprep = nset + nsplit + 64 + 64 + 16;

    // ---- prep (cnt=1 || x split || W transposes+split) ----
    hipLaunchKernelGGL(k_prep, dim3(nprep), dim3(256), 0, stream,
                       cnt, N, x, S0hi, S0lo, n8,
                       W1, Wt1hi, Wt1lo, W2, Wt2hi, Wt2lo, W3, Wt3hi, Wt3lo,
                       nset, nsplit);

    // ---- CSR build (by dst) ----
    const int nb = (N + 1023) / 1024;
    hipLaunchKernelGGL(k_count,     dim3((E + 255) / 256),  dim3(256), 0, stream, ei + E, cnt, E);
    hipLaunchKernelGGL(k_scan_local,dim3(nb),               dim3(256), 0, stream, cnt, ptr, bsum, N);
    hipLaunchKernelGGL(k_scan_add2, dim3((N + 256) / 256),  dim3(256), 0, stream, ptr, bsum, N, Et);
    hipLaunchKernelGGL(k_copy,      dim3((N + 255) / 256),  dim3(256), 0, stream, fptr, ptr, N);
    hipLaunchKernelGGL(k_fillcsr,   dim3((Et + 255) / 256), dim3(256), 0, stream, ei, fptr, srcs, E, Et);

    const dim3 gN4((N + 3) / 4);
    const int gx = (N + 63) / 64;

    // ---- layer 1 ----
    hipLaunchKernelGGL((k_gemm_s<8, 32>), dim3(gx, 4), dim3(256), 0, stream,
                       S0hi, S0lo, Wt1hi, Wt1lo, as1, ad1, hB, als, ald, N);
    hipLaunchKernelGGL((k_agg6<8, 32, 4, 8, true>), gN4, dim3(256), 0, stream,
                       hB, als, ald, ptr, srcs, b1, S1hi, S1lo, nullptr, N, 1);
    // ---- layer 2 ----
    hipLaunchKernelGGL((k_gemm_s<8, 32>), dim3(gx, 4), dim3(256), 0, stream,
                       S1hi, S1lo, Wt2hi, Wt2lo, as2, ad2, hB, als, ald, N);
    hipLaunchKernelGGL((k_agg6<8, 32, 4, 8, true>), gN4, dim3(256), 0, stream,
                       hB, als, ald, ptr, srcs, b2, S0hi, S0lo, nullptr, N, 1);
    // ---- layer 3 ----
    hipLaunchKernelGGL((k_gemm_s<1, 64>), dim3(gx, 1), dim3(256), 0, stream,
                       S0hi, S0lo, Wt3hi, Wt3lo, as3, ad3, hB, als, ald, N);
    hipLaunchKernelGGL((k_agg6<1, 64, 1, 2, false>), gN4, dim3(256), 0, stream,
                       hB, als, ald, ptr, srcs, b3, nullptr, nullptr, (float*)d_out, N, 0);
}

// Round 10
// 403.853 us; speedup vs baseline: 2.3907x; 1.0224x over previous
//
#include <hip/hip_runtime.h>
#include <math.h>

#define NSLOPE 0.2f

typedef __attribute__((ext_vector_type(8))) short bf16x8;
typedef __attribute__((ext_vector_type(8))) unsigned short ushort8;
typedef __attribute__((ext_vector_type(4))) float f32x4;

static __device__ __forceinline__ float leaky(float e) {
    return e > 0.f ? e : NSLOPE * e;
}

static __device__ __forceinline__ float bfu(unsigned short u) {
    return __uint_as_float(((unsigned)u) << 16);
}

static __device__ __forceinline__ unsigned short f2bf_rne(float f) {
    unsigned b = __float_as_uint(f);
    unsigned r = b + 0x7fffu + ((b >> 16) & 1u);
    return (unsigned short)(r >> 16);
}

static __device__ __forceinline__ void split1(float f, unsigned short& hi,
                                              unsigned short& lo) {
    unsigned b = __float_as_uint(f);
    unsigned hb = b & 0xffff0000u;
    hi = (unsigned short)(hb >> 16);
    lo = (unsigned short)(__float_as_uint(f - __uint_as_float(hb)) >> 16);
}

// ---------------- CSR build ----------------

__global__ void k_count(const int* __restrict__ dst, int* __restrict__ cnt, int E) {
    int i = blockIdx.x * blockDim.x + threadIdx.x;
    if (i < E) atomicAdd(&cnt[dst[i]], 1);
}

__global__ void k_scan_local(const int* __restrict__ cnt, int* __restrict__ ptr,
                             int* __restrict__ bsum, int N) {
    __shared__ int sd[256];
    int t = threadIdx.x;
    int i0 = blockIdx.x * 1024 + t * 4;
    int v0 = (i0 + 0 < N) ? cnt[i0 + 0] : 0;
    int v1 = (i0 + 1 < N) ? cnt[i0 + 1] : 0;
    int v2 = (i0 + 2 < N) ? cnt[i0 + 2] : 0;
    int v3 = (i0 + 3 < N) ? cnt[i0 + 3] : 0;
    int ts = v0 + v1 + v2 + v3;
    sd[t] = ts;
    __syncthreads();
    for (int o = 1; o < 256; o <<= 1) {
        int add = (t >= o) ? sd[t - o] : 0;
        __syncthreads();
        sd[t] += add;
        __syncthreads();
    }
    int run = sd[t] - ts;
    if (i0 + 0 < N) ptr[i0 + 0] = run; run += v0;
    if (i0 + 1 < N) ptr[i0 + 1] = run; run += v1;
    if (i0 + 2 < N) ptr[i0 + 2] = run; run += v2;
    if (i0 + 3 < N) ptr[i0 + 3] = run;
    if (t == 255) bsum[blockIdx.x] = sd[255];
}

__global__ void k_scan_add2(int* __restrict__ ptr, const int* __restrict__ bsum,
                            int N, int Et) {
    __shared__ int base;
    const int chunk = blockIdx.x >> 2;
    if (threadIdx.x == 0) {
        int s = 0;
        for (int b = 0; b < chunk; ++b) s += bsum[b];
        base = s;
    }
    __syncthreads();
    int i = blockIdx.x * 256 + threadIdx.x;
    if (i < N) ptr[i] += base;
    else if (i == N) ptr[N] = Et;
}

__global__ void k_copy(int* __restrict__ d, const int* __restrict__ s, int N) {
    int i = blockIdx.x * blockDim.x + threadIdx.x;
    if (i < N) d[i] = s[i];
}

__global__ void k_fillcsr(const int* __restrict__ ei, int* __restrict__ fptr,
                          int* __restrict__ srcs, int E, int Et) {
    int i = blockIdx.x * blockDim.x + threadIdx.x;
    if (i >= Et) return;
    int s, d;
    if (i < E) { s = ei[i]; d = ei[E + i]; }
    else       { s = d = i - E; }
    int pos = atomicAdd(&fptr[d], 1);
    srcs[pos] = s;
}

// ---------------- fused prep: cnt=1  ||  x split  ||  3x W transpose+split ---
__global__ __launch_bounds__(256) void k_prep(
    int* __restrict__ cnt, int N,
    const float* __restrict__ x, unsigned short* __restrict__ xhi,
    unsigned short* __restrict__ xlo, int n8,
    const float* __restrict__ W1, unsigned short* __restrict__ w1h, unsigned short* __restrict__ w1l,
    const float* __restrict__ W2, unsigned short* __restrict__ w2h, unsigned short* __restrict__ w2l,
    const float* __restrict__ W3, unsigned short* __restrict__ w3h, unsigned short* __restrict__ w3l,
    int nset, int nsplit) {
    __shared__ float tile[32][33];
    const int b = blockIdx.x;
    const int tid = threadIdx.x;
    if (b < nset) {
        int i = b * 256 + tid;
        if (i < N) cnt[i] = 1;
    } else if (b < nset + nsplit) {
        int i = (b - nset) * 256 + tid;
        if (i < n8) {
            const float4 v0 = *reinterpret_cast<const float4*>(&x[(size_t)i * 8]);
            const float4 v1 = *reinterpret_cast<const float4*>(&x[(size_t)i * 8 + 4]);
            const float f[8] = {v0.x, v0.y, v0.z, v0.w, v1.x, v1.y, v1.z, v1.w};
            ushort8 h, l;
#pragma unroll
            for (int j = 0; j < 8; ++j) {
                unsigned short hj, lj;
                split1(f[j], hj, lj);
                h[j] = hj; l[j] = lj;
            }
            *reinterpret_cast<ushort8*>(&xhi[(size_t)i * 8]) = h;
            *reinterpret_cast<ushort8*>(&xlo[(size_t)i * 8]) = l;
        }
    } else {
        int tb = b - nset - nsplit;     // 0..143
        const float* B; unsigned short *H, *L;
        int M, bx, by;
        if (tb < 64)       { B = W1; H = w1h; L = w1l; M = 256; bx = (tb & 7) * 32; by = (tb >> 3) * 32; }
        else if (tb < 128) { tb -= 64;  B = W2; H = w2h; L = w2l; M = 256; bx = (tb & 7) * 32; by = (tb >> 3) * 32; }
        else               { tb -= 128; B = W3; H = w3h; L = w3l; M = 64;  bx = (tb & 1) * 32; by = (tb >> 1) * 32; }
        constexpr int K = 256;
        const int tx = tid & 31, ty = tid >> 5;
        for (int r = ty; r < 32; r += 8) tile[r][tx] = B[(size_t)(by + r) * M + bx + tx];
        __syncthreads();
        for (int r = ty; r < 32; r += 8) {
            unsigned short h, l;
            split1(tile[tx][r], h, l);
            H[(size_t)(bx + r) * K + by + tx] = h;
            L[(size_t)(bx + r) * K + by + tx] = l;
        }
    }
}

// ---------------- wide GEMM for layers 1-2: BN = M = 256, one A read --------
// Block: 256 thr = 4 waves; wave w owns all 64 rows x cols [w*64, w*64+64).
// Numerically identical to k_gemm_s (same per-output MFMA sequence).
__global__ __launch_bounds__(256) void k_gemm2(const unsigned short* __restrict__ Ahi,
                                               const unsigned short* __restrict__ Alo,
                                               const unsigned short* __restrict__ Whi,
                                               const unsigned short* __restrict__ Wlo,
                                               const float* __restrict__ asrc,
                                               const float* __restrict__ adst,
                                               unsigned short* __restrict__ hb,
                                               float* __restrict__ als,
                                               float* __restrict__ ald,
                                               int N) {
    constexpr int K = 256;
    constexpr int M = 256;
    __shared__ unsigned short Ah[64][36], Al[64][36];
    __shared__ unsigned short Bh[256][36], Bl[256][36];
    const int tid = threadIdx.x;
    const int lane = tid & 63;
    const int wid = tid >> 6;
    const int row0 = blockIdx.x * 64;

    const int sr = tid >> 2;
    const int sk = (tid & 3) << 3;
    const int ga = row0 + sr;
    const size_t gaK = (size_t)ga * K;

    const int wc0 = wid * 64;           // wave col offset
    const int fr = lane & 15;
    const int ko = (lane >> 4) * 8;

    f32x4 acc[4][4];
#pragma unroll
    for (int i = 0; i < 4; ++i)
#pragma unroll
        for (int j = 0; j < 4; ++j) acc[i][j] = (f32x4){0.f, 0.f, 0.f, 0.f};

    for (int k0 = 0; k0 < K; k0 += 32) {
        ushort8 ah = {0,0,0,0,0,0,0,0}, al = {0,0,0,0,0,0,0,0};
        if (ga < N) {
            ah = *reinterpret_cast<const ushort8*>(&Ahi[gaK + k0 + sk]);
            al = *reinterpret_cast<const ushort8*>(&Alo[gaK + k0 + sk]);
        }
        *reinterpret_cast<ushort8*>(&Ah[sr][sk]) = ah;
        *reinterpret_cast<ushort8*>(&Al[sr][sk]) = al;
#pragma unroll
        for (int p = 0; p < 4; ++p) {
            const int m = sr + 64 * p;
            const size_t gm = (size_t)m * K + k0 + sk;
            *reinterpret_cast<ushort8*>(&Bh[m][sk]) =
                *reinterpret_cast<const ushort8*>(&Whi[gm]);
            *reinterpret_cast<ushort8*>(&Bl[m][sk]) =
                *reinterpret_cast<const ushort8*>(&Wlo[gm]);
        }
        __syncthreads();

        bf16x8 ahi[4], alo4[4];
#pragma unroll
        for (int i = 0; i < 4; ++i) {
            ahi[i]  = *reinterpret_cast<const bf16x8*>(&Ah[i * 16 + fr][ko]);
            alo4[i] = *reinterpret_cast<const bf16x8*>(&Al[i * 16 + fr][ko]);
        }
#pragma unroll
        for (int j = 0; j < 4; ++j) {
            const bf16x8 bh = *reinterpret_cast<const bf16x8*>(&Bh[wc0 + j * 16 + fr][ko]);
            const bf16x8 bl = *reinterpret_cast<const bf16x8*>(&Bl[wc0 + j * 16 + fr][ko]);
#pragma unroll
            for (int i = 0; i < 4; ++i) {
                acc[i][j] = __builtin_amdgcn_mfma_f32_16x16x32_bf16(ahi[i], bh, acc[i][j], 0, 0, 0);
                acc[i][j] = __builtin_amdgcn_mfma_f32_16x16x32_bf16(ahi[i], bl, acc[i][j], 0, 0, 0);
                acc[i][j] = __builtin_amdgcn_mfma_f32_16x16x32_bf16(alo4[i], bh, acc[i][j], 0, 0, 0);
            }
        }
        __syncthreads();
    }

    const int orow = (lane >> 4) * 4;
    const int ocol = lane & 15;

    // ---- hb store ----
#pragma unroll
    for (int i = 0; i < 4; ++i) {
#pragma unroll
        for (int r = 0; r < 4; ++r) {
            const int row = row0 + i * 16 + orow + r;
            if (row < N) {
#pragma unroll
                for (int j = 0; j < 4; ++j) {
                    const int col = wc0 + j * 16 + ocol;
                    hb[(size_t)row * M + col] = f2bf_rne(acc[i][j][r]);
                }
            }
        }
    }

    // ---- fused logits: wave w covers heads 2w (j=0,1) and 2w+1 (j=2,3) ----
    const float as0 = asrc[wc0 + ocol],      as1 = asrc[wc0 + 16 + ocol];
    const float as2 = asrc[wc0 + 32 + ocol], as3 = asrc[wc0 + 48 + ocol];
    const float ad0 = adst[wc0 + ocol],      ad1 = adst[wc0 + 16 + ocol];
    const float ad2 = adst[wc0 + 32 + ocol], ad3 = adst[wc0 + 48 + ocol];
    const int headA = wc0 >> 5, headB = headA + 1;

#pragma unroll
    for (int i = 0; i < 4; ++i) {
#pragma unroll
        for (int r = 0; r < 4; ++r) {
            float psA = acc[i][0][r] * as0 + acc[i][1][r] * as1;
            float pdA = acc[i][0][r] * ad0 + acc[i][1][r] * ad1;
            float psB = acc[i][2][r] * as2 + acc[i][3][r] * as3;
            float pdB = acc[i][2][r] * ad2 + acc[i][3][r] * ad3;
#pragma unroll
            for (int o = 1; o < 16; o <<= 1) {
                psA += __shfl_xor(psA, o);
                pdA += __shfl_xor(pdA, o);
                psB += __shfl_xor(psB, o);
                pdB += __shfl_xor(pdB, o);
            }
            const int row = row0 + i * 16 + orow + r;
            if (ocol == 0 && row < N) {
                als[(size_t)row * 8 + headA] = psA;
                ald[(size_t)row * 8 + headA] = pdA;
                als[(size_t)row * 8 + headB] = psB;
                ald[(size_t)row * 8 + headB] = pdB;
            }
        }
    }
}

// ---------------- layer-3 GEMM (round-9 verbatim, M=64) ----------------

template <int HN, int CN>
__global__ __launch_bounds__(256) void k_gemm_s(const unsigned short* __restrict__ Ahi,
                                                const unsigned short* __restrict__ Alo,
                                                const unsigned short* __restrict__ Whi,
                                                const unsigned short* __restrict__ Wlo,
                                                const float* __restrict__ asrc,
                                                const float* __restrict__ adst,
                                                unsigned short* __restrict__ hb,
                                                float* __restrict__ als,
                                                float* __restrict__ ald,
                                                int N) {
    constexpr int K = 256;
    constexpr int M = HN * CN;
    __shared__ unsigned short Ah[64][40], Al[64][40], Bh[64][40], Bl[64][40];
    const int tid = threadIdx.x;
    const int lane = tid & 63;
    const int wid = tid >> 6;
    const int row0 = blockIdx.x * 64;
    const int col0 = blockIdx.y * 64;

    const int sr = tid >> 2;
    const int sk = (tid & 3) << 3;
    const int ga = row0 + sr;
    const size_t gaK = (size_t)ga * K;
    const size_t gcK = (size_t)(col0 + sr) * K;

    const int wr = (wid >> 1) * 32;
    const int wc = (wid & 1) * 32;
    const int fr = lane & 15;
    const int ko = (lane >> 4) * 8;

    f32x4 acc[2][2];
#pragma unroll
    for (int i = 0; i < 2; ++i)
#pragma unroll
        for (int j = 0; j < 2; ++j) acc[i][j] = (f32x4){0.f, 0.f, 0.f, 0.f};

    for (int k0 = 0; k0 < K; k0 += 32) {
        ushort8 ah = {0,0,0,0,0,0,0,0}, al = {0,0,0,0,0,0,0,0};
        if (ga < N) {
            ah = *reinterpret_cast<const ushort8*>(&Ahi[gaK + k0 + sk]);
            al = *reinterpret_cast<const ushort8*>(&Alo[gaK + k0 + sk]);
        }
        const ushort8 bh = *reinterpret_cast<const ushort8*>(&Whi[gcK + k0 + sk]);
        const ushort8 bl = *reinterpret_cast<const ushort8*>(&Wlo[gcK + k0 + sk]);
        *reinterpret_cast<ushort8*>(&Ah[sr][sk]) = ah;
        *reinterpret_cast<ushort8*>(&Al[sr][sk]) = al;
        *reinterpret_cast<ushort8*>(&Bh[sr][sk]) = bh;
        *reinterpret_cast<ushort8*>(&Bl[sr][sk]) = bl;
        __syncthreads();

        bf16x8 ahi[2], alo[2], bhi[2], blo[2];
#pragma unroll
        for (int i = 0; i < 2; ++i) {
            ahi[i] = *reinterpret_cast<const bf16x8*>(&Ah[wr + i * 16 + fr][ko]);
            alo[i] = *reinterpret_cast<const bf16x8*>(&Al[wr + i * 16 + fr][ko]);
        }
#pragma unroll
        for (int j = 0; j < 2; ++j) {
            bhi[j] = *reinterpret_cast<const bf16x8*>(&Bh[wc + j * 16 + fr][ko]);
            blo[j] = *reinterpret_cast<const bf16x8*>(&Bl[wc + j * 16 + fr][ko]);
        }
#pragma unroll
        for (int i = 0; i < 2; ++i)
#pragma unroll
            for (int j = 0; j < 2; ++j) {
                acc[i][j] = __builtin_amdgcn_mfma_f32_16x16x32_bf16(ahi[i], bhi[j], acc[i][j], 0, 0, 0);
                acc[i][j] = __builtin_amdgcn_mfma_f32_16x16x32_bf16(ahi[i], blo[j], acc[i][j], 0, 0, 0);
                acc[i][j] = __builtin_amdgcn_mfma_f32_16x16x32_bf16(alo[i], bhi[j], acc[i][j], 0, 0, 0);
            }
        __syncthreads();
    }

    const int orow = (lane >> 4) * 4;
    const int ocol = lane & 15;

#pragma unroll
    for (int i = 0; i < 2; ++i) {
#pragma unroll
        for (int r = 0; r < 4; ++r) {
            const int row = row0 + wr + i * 16 + orow + r;
            if (row < N) {
#pragma unroll
                for (int j = 0; j < 2; ++j) {
                    const int col = col0 + wc + j * 16 + ocol;
                    hb[(size_t)row * M + col] = f2bf_rne(acc[i][j][r]);
                }
            }
        }
    }

    const int c0 = col0 + wc;
    const float as0 = asrc[c0 + ocol],      as1 = asrc[c0 + 16 + ocol];
    const float ad0 = adst[c0 + ocol],      ad1 = adst[c0 + 16 + ocol];

    {
        __shared__ float part[2][64][2];
#pragma unroll
        for (int i = 0; i < 2; ++i) {
#pragma unroll
            for (int r = 0; r < 4; ++r) {
                float ps = acc[i][0][r] * as0 + acc[i][1][r] * as1;
                float pd = acc[i][0][r] * ad0 + acc[i][1][r] * ad1;
#pragma unroll
                for (int o = 1; o < 16; o <<= 1) {
                    ps += __shfl_xor(ps, o);
                    pd += __shfl_xor(pd, o);
                }
                if (ocol == 0) {
                    const int lr = wr + i * 16 + orow + r;
                    part[wc >> 5][lr][0] = ps;
                    part[wc >> 5][lr][1] = pd;
                }
            }
        }
        __syncthreads();
        if (tid < 64) {
            const int row = row0 + tid;
            if (row < N) {
                als[row] = part[0][tid][0] + part[1][tid][0];
                ald[row] = part[0][tid][1] + part[1][tid][1];
            }
        }
    }
}

// ---------------- per-node softmax + aggregate (round-9 verbatim) -----------
template <int HN, int CN, int VEC, int P, bool OSPLIT>
__global__ __launch_bounds__(256) void k_agg6(const unsigned short* __restrict__ hb,
                                              const float* __restrict__ als,
                                              const float* __restrict__ ald,
                                              const int* __restrict__ ptr,
                                              const int* __restrict__ srcs,
                                              const float* __restrict__ bias,
                                              unsigned short* __restrict__ ohi,
                                              unsigned short* __restrict__ olo,
                                              float* __restrict__ out,
                                              int N, int relu) {
    constexpr int HC = HN * CN;
    constexpr int SUBS = 64 / HN;
    constexpr int GB = (SUBS < 16) ? SUBS : 16;
    const int l = threadIdx.x & 63;
    const int n = blockIdx.x * 4 + (threadIdx.x >> 6);
    if (n >= N) return;
    const int beg = ptr[n], end = ptr[n + 1];
    const int hd_e = l % HN;
    const int sub = l / HN;
    const float aldv = ald[(unsigned)n * HN + hd_e];

    float p[P];
    int   sr[P];
    float ssum = 0.f;
#pragma unroll
    for (int b = 0; b < P; ++b) {
        const int j = beg + b * SUBS + sub;
        float pv = 0.f; int s = 0;
        if (j < end) {
            s = srcs[j];
            pv = __expf(leaky(als[(unsigned)s * HN + hd_e] + aldv));
        }
        sr[b] = s; p[b] = pv; ssum += pv;
    }
    for (int j = beg + P * SUBS + sub; j < end; j += SUBS) {
        ssum += __expf(leaky(als[(unsigned)srcs[j] * HN + hd_e] + aldv));
    }
#pragma unroll
    for (int o = HN; o < 64; o <<= 1) ssum += __shfl_xor(ssum, o);
    const float inv = 1.f / (ssum + 1e-16f);

    const int ch = l * VEC;
    const int hl = ch / CN;
    float acc[VEC];
#pragma unroll
    for (int v = 0; v < VEC; ++v) acc[v] = 0.f;

#pragma unroll
    for (int b = 0; b < P; ++b) {
        const int j0 = beg + b * SUBS;
        if (j0 >= end) break;
        const float am = p[b] * inv;
#pragma unroll
        for (int cb = 0; cb < SUBS / GB; ++cb) {
            if (j0 + cb * GB >= end) break;
            float av[GB];
            if constexpr (VEC == 4) {
                ushort4 hv[GB];
#pragma unroll
                for (int c = 0; c < GB; ++c) {
                    const int ce = cb * GB + c;
                    const int s = __shfl(sr[b], ce * HN);
                    av[c] = __shfl(am, ce * HN + hl);
                    hv[c] = *reinterpret_cast<const ushort4*>(&hb[(unsigned)s * HC + ch]);
                }
#pragma unroll
                for (int c = 0; c < GB; ++c) {
                    acc[0] += av[c] * bfu(hv[c].x);
                    acc[1] += av[c] * bfu(hv[c].y);
                    acc[2] += av[c] * bfu(hv[c].z);
                    acc[3] += av[c] * bfu(hv[c].w);
                }
            } else {
                unsigned short hv[GB];
#pragma unroll
                for (int c = 0; c < GB; ++c) {
                    const int ce = cb * GB + c;
                    const int s = __shfl(sr[b], ce * HN);
                    av[c] = __shfl(am, ce * HN + hl);
                    hv[c] = hb[(unsigned)s * HC + ch];
                }
#pragma unroll
                for (int c = 0; c < GB; ++c) acc[0] += av[c] * bfu(hv[c]);
            }
        }
    }
    for (int j0 = beg + P * SUBS; j0 < end; j0 += SUBS) {
        const int j = j0 + sub;
        int sm = 0; float am = 0.f;
        if (j < end) {
            sm = srcs[j];
            am = __expf(leaky(als[(unsigned)sm * HN + hd_e] + aldv)) * inv;
        }
#pragma unroll
        for (int cb = 0; cb < SUBS / GB; ++cb) {
            if (j0 + cb * GB >= end) break;
            float av[GB];
            if constexpr (VEC == 4) {
                ushort4 hv[GB];
#pragma unroll
                for (int c = 0; c < GB; ++c) {
                    const int ce = cb * GB + c;
                    const int s = __shfl(sm, ce * HN);
                    av[c] = __shfl(am, ce * HN + hl);
                    hv[c] = *reinterpret_cast<const ushort4*>(&hb[(unsigned)s * HC + ch]);
                }
#pragma unroll
                for (int c = 0; c < GB; ++c) {
                    acc[0] += av[c] * bfu(hv[c].x);
                    acc[1] += av[c] * bfu(hv[c].y);
                    acc[2] += av[c] * bfu(hv[c].z);
                    acc[3] += av[c] * bfu(hv[c].w);
                }
            } else {
                unsigned short hv[GB];
#pragma unroll
                for (int c = 0; c < GB; ++c) {
                    const int ce = cb * GB + c;
                    const int s = __shfl(sm, ce * HN);
                    av[c] = __shfl(am, ce * HN + hl);
                    hv[c] = hb[(unsigned)s * HC + ch];
                }
#pragma unroll
                for (int c = 0; c < GB; ++c) acc[0] += av[c] * bfu(hv[c]);
            }
        }
    }

#pragma unroll
    for (int v = 0; v < VEC; ++v) {
        float o = acc[v] + bias[ch + v];
        if (relu) o = fmaxf(o, 0.f);
        acc[v] = o;
    }
    if constexpr (OSPLIT) {
        ushort4 ho, lo4;
        unsigned short h0, l0;
        split1(acc[0], h0, l0); ho.x = h0; lo4.x = l0;
        split1(acc[1], h0, l0); ho.y = h0; lo4.y = l0;
        split1(acc[2], h0, l0); ho.z = h0; lo4.z = l0;
        split1(acc[3], h0, l0); ho.w = h0; lo4.w = l0;
        *reinterpret_cast<ushort4*>(&ohi[(unsigned)n * HC + ch]) = ho;
        *reinterpret_cast<ushort4*>(&olo[(unsigned)n * HC + ch]) = lo4;
    } else if constexpr (VEC == 4) {
        float4 vout;
        vout.x = acc[0]; vout.y = acc[1]; vout.z = acc[2]; vout.w = acc[3];
        *reinterpret_cast<float4*>(&out[(unsigned)n * HC + ch]) = vout;
    } else {
        out[(unsigned)n * HC + ch] = acc[0];
    }
}

// ---------------- launch ----------------

extern "C" void kernel_launch(void* const* d_in, const int* in_sizes, int n_in,
                              void* d_out, int out_size, void* d_ws, size_t ws_size,
                              hipStream_t stream) {
    const float* x   = (const float*)d_in[0];
    const int*   ei  = (const int*)d_in[1];
    const float* W1  = (const float*)d_in[2];
    const float* as1 = (const float*)d_in[3];
    const float* ad1 = (const float*)d_in[4];
    const float* b1  = (const float*)d_in[5];
    const float* W2  = (const float*)d_in[6];
    const float* as2 = (const float*)d_in[7];
    const float* ad2 = (const float*)d_in[8];
    const float* b2  = (const float*)d_in[9];
    const float* W3  = (const float*)d_in[10];
    const float* as3 = (const float*)d_in[11];
    const float* ad3 = (const float*)d_in[12];
    const float* b3  = (const float*)d_in[13];

    const int F  = 256;
    const int N  = in_sizes[0] / F;     // 50000
    const int E  = in_sizes[1] / 2;     // 800000
    const int Et = E + N;

    char* w = (char*)d_ws;
    auto alloc = [&](size_t bytes) {
        char* p = w;
        w += (bytes + 255) & ~(size_t)255;
        return p;
    };
    unsigned short* S0hi = (unsigned short*)alloc((size_t)N * F * 2);
    unsigned short* S0lo = (unsigned short*)alloc((size_t)N * F * 2);
    unsigned short* S1hi = (unsigned short*)alloc((size_t)N * F * 2);
    unsigned short* S1lo = (unsigned short*)alloc((size_t)N * F * 2);
    unsigned short* hB   = (unsigned short*)alloc((size_t)N * F * 2);
    unsigned short* Wt1hi = (unsigned short*)alloc((size_t)256 * 256 * 2);
    unsigned short* Wt1lo = (unsigned short*)alloc((size_t)256 * 256 * 2);
    unsigned short* Wt2hi = (unsigned short*)alloc((size_t)256 * 256 * 2);
    unsigned short* Wt2lo = (unsigned short*)alloc((size_t)256 * 256 * 2);
    unsigned short* Wt3hi = (unsigned short*)alloc((size_t)64 * 256 * 2);
    unsigned short* Wt3lo = (unsigned short*)alloc((size_t)64 * 256 * 2);
    float* als  = (float*)alloc((size_t)N * 8 * 4);
    float* ald  = (float*)alloc((size_t)N * 8 * 4);
    int*   cnt  = (int*)alloc((size_t)N * 4);
    int*   ptr  = (int*)alloc((size_t)(N + 1) * 4);
    int*   fptr = (int*)alloc((size_t)(N + 1) * 4);
    int*   srcs = (int*)alloc((size_t)Et * 4);
    int*   bsum = (int*)alloc(4096);

    const int n8 = N * F / 8;
    const int nset = (N + 255) / 256;
    const int nsplit = (n8 + 255) / 256;
    const int nprep = nset + nsplit + 64 + 64 + 16;

    hipLaunchKernelGGL(k_prep, dim3(nprep), dim3(256), 0, stream,
                       cnt, N, x, S0hi, S0lo, n8,
                       W1, Wt1hi, Wt1lo, W2, Wt2hi, Wt2lo, W3, Wt3hi, Wt3lo,
                       nset, nsplit);

    const int nb = (N + 1023) / 1024;
    hipLaunchKernelGGL(k_count,     dim3((E + 255) / 256),  dim3(256), 0, stream, ei + E, cnt, E);
    hipLaunchKernelGGL(k_scan_local,dim3(nb),               dim3(256), 0, stream, cnt, ptr, bsum, N);
    hipLaunchKernelGGL(k_scan_add2, dim3((N + 256) / 256),  dim3(256), 0, stream, ptr, bsum, N, Et);
    hipLaunchKernelGGL(k_copy,      dim3((N + 255) / 256),  dim3(256), 0, stream, fptr, ptr, N);
    hipLaunchKernelGGL(k_fillcsr,   dim3((Et + 255) / 256), dim3(256), 0, stream, ei, fptr, srcs, E, Et);

    const dim3 gN4((N + 3) / 4);
    const int gx = (N + 63) / 64;

    // ---- layer 1 ----
    hipLaunchKernelGGL(k_gemm2, dim3(gx), dim3(256), 0, stream,
                       S0hi, S0lo, Wt1hi, Wt1lo, as1, ad1, hB, als, ald, N);
    hipLaunchKernelGGL((k_agg6<8, 32, 4, 8, true>), gN4, dim3(256), 0, stream,
                       hB, als, ald, ptr, srcs, b1, S1hi, S1lo, nullptr, N, 1);
    // ---- layer 2 ----
    hipLaunchKernelGGL(k_gemm2, dim3(gx), dim3(256), 0, stream,
                       S1hi, S1lo, Wt2hi, Wt2lo, as2, ad2, hB, als, ald, N);
    hipLaunchKernelGGL((k_agg6<8, 32, 4, 8, true>), gN4, dim3(256), 0, stream,
                       hB, als, ald, ptr, srcs, b2, S0hi, S0lo, nullptr, N, 1);
    // ---- layer 3 ----
    hipLaunchKernelGGL((k_gemm_s<1, 64>), dim3(gx, 1), dim3(256), 0, stream,
                       S0hi, S0lo, Wt3hi, Wt3lo, as3, ad3, hB, als, ald, N);
    hipLaunchKernelGGL((k_agg6<1, 64, 1, 2, false>), gN4, dim3(256), 0, stream,
                       hB, als, ald, ptr, srcs, b3, nullptr, nullptr, (float*)d_out, N, 0);
}

// Round 12
// 381.119 us; speedup vs baseline: 2.5333x; 1.0597x over previous
//
#include <hip/hip_runtime.h>
#include <math.h>

#define NSLOPE 0.2f

typedef __attribute__((ext_vector_type(8))) short bf16x8;
typedef __attribute__((ext_vector_type(8))) unsigned short ushort8;
typedef __attribute__((ext_vector_type(4))) float f32x4;

static __device__ __forceinline__ float leaky(float e) {
    return e > 0.f ? e : NSLOPE * e;
}

static __device__ __forceinline__ float bfu(unsigned short u) {
    return __uint_as_float(((unsigned)u) << 16);
}

static __device__ __forceinline__ unsigned short f2bf_rne(float f) {
    unsigned b = __float_as_uint(f);
    unsigned r = b + 0x7fffu + ((b >> 16) & 1u);
    return (unsigned short)(r >> 16);
}

static __device__ __forceinline__ void split1(float f, unsigned short& hi,
                                              unsigned short& lo) {
    unsigned b = __float_as_uint(f);
    unsigned hb = b & 0xffff0000u;
    hi = (unsigned short)(hb >> 16);
    lo = (unsigned short)(__float_as_uint(f - __uint_as_float(hb)) >> 16);
}

// ---------------- CSR build ----------------

__global__ void k_count(const int* __restrict__ dst, int* __restrict__ cnt, int E) {
    int i = blockIdx.x * blockDim.x + threadIdx.x;
    if (i < E) atomicAdd(&cnt[dst[i]], 1);
}

__global__ void k_scan_local(const int* __restrict__ cnt, int* __restrict__ ptr,
                             int* __restrict__ bsum, int N) {
    __shared__ int sd[256];
    int t = threadIdx.x;
    int i0 = blockIdx.x * 1024 + t * 4;
    int v0 = (i0 + 0 < N) ? cnt[i0 + 0] : 0;
    int v1 = (i0 + 1 < N) ? cnt[i0 + 1] : 0;
    int v2 = (i0 + 2 < N) ? cnt[i0 + 2] : 0;
    int v3 = (i0 + 3 < N) ? cnt[i0 + 3] : 0;
    int ts = v0 + v1 + v2 + v3;
    sd[t] = ts;
    __syncthreads();
    for (int o = 1; o < 256; o <<= 1) {
        int add = (t >= o) ? sd[t - o] : 0;
        __syncthreads();
        sd[t] += add;
        __syncthreads();
    }
    int run = sd[t] - ts;
    if (i0 + 0 < N) ptr[i0 + 0] = run; run += v0;
    if (i0 + 1 < N) ptr[i0 + 1] = run; run += v1;
    if (i0 + 2 < N) ptr[i0 + 2] = run; run += v2;
    if (i0 + 3 < N) ptr[i0 + 3] = run;
    if (t == 255) bsum[blockIdx.x] = sd[255];
}

__global__ void k_scan_add2(int* __restrict__ ptr, const int* __restrict__ bsum,
                            int N, int Et) {
    __shared__ int base;
    const int chunk = blockIdx.x >> 2;
    if (threadIdx.x == 0) {
        int s = 0;
        for (int b = 0; b < chunk; ++b) s += bsum[b];
        base = s;
    }
    __syncthreads();
    int i = blockIdx.x * 256 + threadIdx.x;
    if (i < N) ptr[i] += base;
    else if (i == N) ptr[N] = Et;
}

__global__ void k_copy(int* __restrict__ d, const int* __restrict__ s, int N) {
    int i = blockIdx.x * blockDim.x + threadIdx.x;
    if (i < N) d[i] = s[i];
}

__global__ void k_fillcsr(const int* __restrict__ ei, int* __restrict__ fptr,
                          int* __restrict__ srcs, int E, int Et) {
    int i = blockIdx.x * blockDim.x + threadIdx.x;
    if (i >= Et) return;
    int s, d;
    if (i < E) { s = ei[i]; d = ei[E + i]; }
    else       { s = d = i - E; }
    int pos = atomicAdd(&fptr[d], 1);
    srcs[pos] = s;
}

// ---------------- fused prep: cnt=1  ||  x split  ||  3x W transpose+split ---
__global__ __launch_bounds__(256) void k_prep(
    int* __restrict__ cnt, int N,
    const float* __restrict__ x, unsigned short* __restrict__ xhi,
    unsigned short* __restrict__ xlo, int n8,
    const float* __restrict__ W1, unsigned short* __restrict__ w1h, unsigned short* __restrict__ w1l,
    const float* __restrict__ W2, unsigned short* __restrict__ w2h, unsigned short* __restrict__ w2l,
    const float* __restrict__ W3, unsigned short* __restrict__ w3h, unsigned short* __restrict__ w3l,
    int nset, int nsplit) {
    __shared__ float tile[32][33];
    const int b = blockIdx.x;
    const int tid = threadIdx.x;
    if (b < nset) {
        int i = b * 256 + tid;
        if (i < N) cnt[i] = 1;
    } else if (b < nset + nsplit) {
        int i = (b - nset) * 256 + tid;
        if (i < n8) {
            const float4 v0 = *reinterpret_cast<const float4*>(&x[(size_t)i * 8]);
            const float4 v1 = *reinterpret_cast<const float4*>(&x[(size_t)i * 8 + 4]);
            const float f[8] = {v0.x, v0.y, v0.z, v0.w, v1.x, v1.y, v1.z, v1.w};
            ushort8 h, l;
#pragma unroll
            for (int j = 0; j < 8; ++j) {
                unsigned short hj, lj;
                split1(f[j], hj, lj);
                h[j] = hj; l[j] = lj;
            }
            *reinterpret_cast<ushort8*>(&xhi[(size_t)i * 8]) = h;
            *reinterpret_cast<ushort8*>(&xlo[(size_t)i * 8]) = l;
        }
    } else {
        int tb = b - nset - nsplit;     // 0..143
        const float* B; unsigned short *H, *L;
        int M, bx, by;
        if (tb < 64)       { B = W1; H = w1h; L = w1l; M = 256; bx = (tb & 7) * 32; by = (tb >> 3) * 32; }
        else if (tb < 128) { tb -= 64;  B = W2; H = w2h; L = w2l; M = 256; bx = (tb & 7) * 32; by = (tb >> 3) * 32; }
        else               { tb -= 128; B = W3; H = w3h; L = w3l; M = 64;  bx = (tb & 1) * 32; by = (tb >> 1) * 32; }
        constexpr int K = 256;
        const int tx = tid & 31, ty = tid >> 5;
        for (int r = ty; r < 32; r += 8) tile[r][tx] = B[(size_t)(by + r) * M + bx + tx];
        __syncthreads();
        for (int r = ty; r < 32; r += 8) {
            unsigned short h, l;
            split1(tile[tx][r], h, l);
            H[(size_t)(bx + r) * K + by + tx] = h;
            L[(size_t)(bx + r) * K + by + tx] = l;
        }
    }
}

// ---------------- wide GEMM for layers 1-2: BN = M = 256, one A read --------
__global__ __launch_bounds__(256) void k_gemm2(const unsigned short* __restrict__ Ahi,
                                               const unsigned short* __restrict__ Alo,
                                               const unsigned short* __restrict__ Whi,
                                               const unsigned short* __restrict__ Wlo,
                                               const float* __restrict__ asrc,
                                               const float* __restrict__ adst,
                                               unsigned short* __restrict__ hb,
                                               float* __restrict__ als,
                                               float* __restrict__ ald,
                                               int N) {
    constexpr int K = 256;
    constexpr int M = 256;
    __shared__ unsigned short Ah[64][36], Al[64][36];
    __shared__ unsigned short Bh[256][36], Bl[256][36];
    const int tid = threadIdx.x;
    const int lane = tid & 63;
    const int wid = tid >> 6;
    const int row0 = blockIdx.x * 64;

    const int sr = tid >> 2;
    const int sk = (tid & 3) << 3;
    const int ga = row0 + sr;
    const size_t gaK = (size_t)ga * K;

    const int wc0 = wid * 64;
    const int fr = lane & 15;
    const int ko = (lane >> 4) * 8;

    f32x4 acc[4][4];
#pragma unroll
    for (int i = 0; i < 4; ++i)
#pragma unroll
        for (int j = 0; j < 4; ++j) acc[i][j] = (f32x4){0.f, 0.f, 0.f, 0.f};

    for (int k0 = 0; k0 < K; k0 += 32) {
        ushort8 ah = {0,0,0,0,0,0,0,0}, al = {0,0,0,0,0,0,0,0};
        if (ga < N) {
            ah = *reinterpret_cast<const ushort8*>(&Ahi[gaK + k0 + sk]);
            al = *reinterpret_cast<const ushort8*>(&Alo[gaK + k0 + sk]);
        }
        *reinterpret_cast<ushort8*>(&Ah[sr][sk]) = ah;
        *reinterpret_cast<ushort8*>(&Al[sr][sk]) = al;
#pragma unroll
        for (int p = 0; p < 4; ++p) {
            const int m = sr + 64 * p;
            const size_t gm = (size_t)m * K + k0 + sk;
            *reinterpret_cast<ushort8*>(&Bh[m][sk]) =
                *reinterpret_cast<const ushort8*>(&Whi[gm]);
            *reinterpret_cast<ushort8*>(&Bl[m][sk]) =
                *reinterpret_cast<const ushort8*>(&Wlo[gm]);
        }
        __syncthreads();

        bf16x8 ahi[4], alo4[4];
#pragma unroll
        for (int i = 0; i < 4; ++i) {
            ahi[i]  = *reinterpret_cast<const bf16x8*>(&Ah[i * 16 + fr][ko]);
            alo4[i] = *reinterpret_cast<const bf16x8*>(&Al[i * 16 + fr][ko]);
        }
#pragma unroll
        for (int j = 0; j < 4; ++j) {
            const bf16x8 bh = *reinterpret_cast<const bf16x8*>(&Bh[wc0 + j * 16 + fr][ko]);
            const bf16x8 bl = *reinterpret_cast<const bf16x8*>(&Bl[wc0 + j * 16 + fr][ko]);
#pragma unroll
            for (int i = 0; i < 4; ++i) {
                acc[i][j] = __builtin_amdgcn_mfma_f32_16x16x32_bf16(ahi[i], bh, acc[i][j], 0, 0, 0);
                acc[i][j] = __builtin_amdgcn_mfma_f32_16x16x32_bf16(ahi[i], bl, acc[i][j], 0, 0, 0);
                acc[i][j] = __builtin_amdgcn_mfma_f32_16x16x32_bf16(alo4[i], bh, acc[i][j], 0, 0, 0);
            }
        }
        __syncthreads();
    }

    const int orow = (lane >> 4) * 4;
    const int ocol = lane & 15;

#pragma unroll
    for (int i = 0; i < 4; ++i) {
#pragma unroll
        for (int r = 0; r < 4; ++r) {
            const int row = row0 + i * 16 + orow + r;
            if (row < N) {
#pragma unroll
                for (int j = 0; j < 4; ++j) {
                    const int col = wc0 + j * 16 + ocol;
                    hb[(size_t)row * M + col] = f2bf_rne(acc[i][j][r]);
                }
            }
        }
    }

    const float as0 = asrc[wc0 + ocol],      as1 = asrc[wc0 + 16 + ocol];
    const float as2 = asrc[wc0 + 32 + ocol], as3 = asrc[wc0 + 48 + ocol];
    const float ad0 = adst[wc0 + ocol],      ad1 = adst[wc0 + 16 + ocol];
    const float ad2 = adst[wc0 + 32 + ocol], ad3 = adst[wc0 + 48 + ocol];
    const int headA = wc0 >> 5, headB = headA + 1;

#pragma unroll
    for (int i = 0; i < 4; ++i) {
#pragma unroll
        for (int r = 0; r < 4; ++r) {
            float psA = acc[i][0][r] * as0 + acc[i][1][r] * as1;
            float pdA = acc[i][0][r] * ad0 + acc[i][1][r] * ad1;
            float psB = acc[i][2][r] * as2 + acc[i][3][r] * as3;
            float pdB = acc[i][2][r] * ad2 + acc[i][3][r] * ad3;
#pragma unroll
            for (int o = 1; o < 16; o <<= 1) {
                psA += __shfl_xor(psA, o);
                pdA += __shfl_xor(pdA, o);
                psB += __shfl_xor(psB, o);
                pdB += __shfl_xor(pdB, o);
            }
            const int row = row0 + i * 16 + orow + r;
            if (ocol == 0 && row < N) {
                als[(size_t)row * 8 + headA] = psA;
                ald[(size_t)row * 8 + headA] = pdA;
                als[(size_t)row * 8 + headB] = psB;
                ald[(size_t)row * 8 + headB] = pdB;
            }
        }
    }
}

// ---------------- layer-3 GEMM (M=64) ----------------

template <int HN, int CN>
__global__ __launch_bounds__(256) void k_gemm_s(const unsigned short* __restrict__ Ahi,
                                                const unsigned short* __restrict__ Alo,
                                                const unsigned short* __restrict__ Whi,
                                                const unsigned short* __restrict__ Wlo,
                                                const float* __restrict__ asrc,
                                                const float* __restrict__ adst,
                                                unsigned short* __restrict__ hb,
                                                float* __restrict__ als,
                                                float* __restrict__ ald,
                                                int N) {
    constexpr int K = 256;
    constexpr int M = HN * CN;
    __shared__ unsigned short Ah[64][40], Al[64][40], Bh[64][40], Bl[64][40];
    const int tid = threadIdx.x;
    const int lane = tid & 63;
    const int wid = tid >> 6;
    const int row0 = blockIdx.x * 64;
    const int col0 = blockIdx.y * 64;

    const int sr = tid >> 2;
    const int sk = (tid & 3) << 3;
    const int ga = row0 + sr;
    const size_t gaK = (size_t)ga * K;
    const size_t gcK = (size_t)(col0 + sr) * K;

    const int wr = (wid >> 1) * 32;
    const int wc = (wid & 1) * 32;
    const int fr = lane & 15;
    const int ko = (lane >> 4) * 8;

    f32x4 acc[2][2];
#pragma unroll
    for (int i = 0; i < 2; ++i)
#pragma unroll
        for (int j = 0; j < 2; ++j) acc[i][j] = (f32x4){0.f, 0.f, 0.f, 0.f};

    for (int k0 = 0; k0 < K; k0 += 32) {
        ushort8 ah = {0,0,0,0,0,0,0,0}, al = {0,0,0,0,0,0,0,0};
        if (ga < N) {
            ah = *reinterpret_cast<const ushort8*>(&Ahi[gaK + k0 + sk]);
            al = *reinterpret_cast<const ushort8*>(&Alo[gaK + k0 + sk]);
        }
        const ushort8 bh = *reinterpret_cast<const ushort8*>(&Whi[gcK + k0 + sk]);
        const ushort8 bl = *reinterpret_cast<const ushort8*>(&Wlo[gcK + k0 + sk]);
        *reinterpret_cast<ushort8*>(&Ah[sr][sk]) = ah;
        *reinterpret_cast<ushort8*>(&Al[sr][sk]) = al;
        *reinterpret_cast<ushort8*>(&Bh[sr][sk]) = bh;
        *reinterpret_cast<ushort8*>(&Bl[sr][sk]) = bl;
        __syncthreads();

        bf16x8 ahi[2], alo[2], bhi[2], blo[2];
#pragma unroll
        for (int i = 0; i < 2; ++i) {
            ahi[i] = *reinterpret_cast<const bf16x8*>(&Ah[wr + i * 16 + fr][ko]);
            alo[i] = *reinterpret_cast<const bf16x8*>(&Al[wr + i * 16 + fr][ko]);
        }
#pragma unroll
        for (int j = 0; j < 2; ++j) {
            bhi[j] = *reinterpret_cast<const bf16x8*>(&Bh[wc + j * 16 + fr][ko]);
            blo[j] = *reinterpret_cast<const bf16x8*>(&Bl[wc + j * 16 + fr][ko]);
        }
#pragma unroll
        for (int i = 0; i < 2; ++i)
#pragma unroll
            for (int j = 0; j < 2; ++j) {
                acc[i][j] = __builtin_amdgcn_mfma_f32_16x16x32_bf16(ahi[i], bhi[j], acc[i][j], 0, 0, 0);
                acc[i][j] = __builtin_amdgcn_mfma_f32_16x16x32_bf16(ahi[i], blo[j], acc[i][j], 0, 0, 0);
                acc[i][j] = __builtin_amdgcn_mfma_f32_16x16x32_bf16(alo[i], bhi[j], acc[i][j], 0, 0, 0);
            }
        __syncthreads();
    }

    const int orow = (lane >> 4) * 4;
    const int ocol = lane & 15;

#pragma unroll
    for (int i = 0; i < 2; ++i) {
#pragma unroll
        for (int r = 0; r < 4; ++r) {
            const int row = row0 + wr + i * 16 + orow + r;
            if (row < N) {
#pragma unroll
                for (int j = 0; j < 2; ++j) {
                    const int col = col0 + wc + j * 16 + ocol;
                    hb[(size_t)row * M + col] = f2bf_rne(acc[i][j][r]);
                }
            }
        }
    }

    const int c0 = col0 + wc;
    const float as0 = asrc[c0 + ocol],      as1 = asrc[c0 + 16 + ocol];
    const float ad0 = adst[c0 + ocol],      ad1 = adst[c0 + 16 + ocol];

    {
        __shared__ float part[2][64][2];
#pragma unroll
        for (int i = 0; i < 2; ++i) {
#pragma unroll
            for (int r = 0; r < 4; ++r) {
                float ps = acc[i][0][r] * as0 + acc[i][1][r] * as1;
                float pd = acc[i][0][r] * ad0 + acc[i][1][r] * ad1;
#pragma unroll
                for (int o = 1; o < 16; o <<= 1) {
                    ps += __shfl_xor(ps, o);
                    pd += __shfl_xor(pd, o);
                }
                if (ocol == 0) {
                    const int lr = wr + i * 16 + orow + r;
                    part[wc >> 5][lr][0] = ps;
                    part[wc >> 5][lr][1] = pd;
                }
            }
        }
        __syncthreads();
        if (tid < 64) {
            const int row = row0 + tid;
            if (row < N) {
                als[row] = part[0][tid][0] + part[1][tid][0];
                ald[row] = part[0][tid][1] + part[1][tid][1];
            }
        }
    }
}

// ---------------- big-layer softmax + aggregate (round-9 verbatim) ----------
template <int HN, int CN, int VEC, int P, bool OSPLIT>
__global__ __launch_bounds__(256) void k_agg6(const unsigned short* __restrict__ hb,
                                              const float* __restrict__ als,
                                              const float* __restrict__ ald,
                                              const int* __restrict__ ptr,
                                              const int* __restrict__ srcs,
                                              const float* __restrict__ bias,
                                              unsigned short* __restrict__ ohi,
                                              unsigned short* __restrict__ olo,
                                              float* __restrict__ out,
                                              int N, int relu) {
    constexpr int HC = HN * CN;
    constexpr int SUBS = 64 / HN;
    constexpr int GB = (SUBS < 16) ? SUBS : 16;
    const int l = threadIdx.x & 63;
    const int n = blockIdx.x * 4 + (threadIdx.x >> 6);
    if (n >= N) return;
    const int beg = ptr[n], end = ptr[n + 1];
    const int hd_e = l % HN;
    const int sub = l / HN;
    const float aldv = ald[(unsigned)n * HN + hd_e];

    float p[P];
    int   sr[P];
    float ssum = 0.f;
#pragma unroll
    for (int b = 0; b < P; ++b) {
        const int j = beg + b * SUBS + sub;
        float pv = 0.f; int s = 0;
        if (j < end) {
            s = srcs[j];
            pv = __expf(leaky(als[(unsigned)s * HN + hd_e] + aldv));
        }
        sr[b] = s; p[b] = pv; ssum += pv;
    }
    for (int j = beg + P * SUBS + sub; j < end; j += SUBS) {
        ssum += __expf(leaky(als[(unsigned)srcs[j] * HN + hd_e] + aldv));
    }
#pragma unroll
    for (int o = HN; o < 64; o <<= 1) ssum += __shfl_xor(ssum, o);
    const float inv = 1.f / (ssum + 1e-16f);

    const int ch = l * VEC;
    const int hl = ch / CN;
    float acc[VEC];
#pragma unroll
    for (int v = 0; v < VEC; ++v) acc[v] = 0.f;

#pragma unroll
    for (int b = 0; b < P; ++b) {
        const int j0 = beg + b * SUBS;
        if (j0 >= end) break;
        const float am = p[b] * inv;
#pragma unroll
        for (int cb = 0; cb < SUBS / GB; ++cb) {
            if (j0 + cb * GB >= end) break;
            float av[GB];
            if constexpr (VEC == 4) {
                ushort4 hv[GB];
#pragma unroll
                for (int c = 0; c < GB; ++c) {
                    const int ce = cb * GB + c;
                    const int s = __shfl(sr[b], ce * HN);
                    av[c] = __shfl(am, ce * HN + hl);
                    hv[c] = *reinterpret_cast<const ushort4*>(&hb[(unsigned)s * HC + ch]);
                }
#pragma unroll
                for (int c = 0; c < GB; ++c) {
                    acc[0] += av[c] * bfu(hv[c].x);
                    acc[1] += av[c] * bfu(hv[c].y);
                    acc[2] += av[c] * bfu(hv[c].z);
                    acc[3] += av[c] * bfu(hv[c].w);
                }
            } else {
                unsigned short hv[GB];
#pragma unroll
                for (int c = 0; c < GB; ++c) {
                    const int ce = cb * GB + c;
                    const int s = __shfl(sr[b], ce * HN);
                    av[c] = __shfl(am, ce * HN + hl);
                    hv[c] = hb[(unsigned)s * HC + ch];
                }
#pragma unroll
                for (int c = 0; c < GB; ++c) acc[0] += av[c] * bfu(hv[c]);
            }
        }
    }
    for (int j0 = beg + P * SUBS; j0 < end; j0 += SUBS) {
        const int j = j0 + sub;
        int sm = 0; float am = 0.f;
        if (j < end) {
            sm = srcs[j];
            am = __expf(leaky(als[(unsigned)sm * HN + hd_e] + aldv)) * inv;
        }
#pragma unroll
        for (int cb = 0; cb < SUBS / GB; ++cb) {
            if (j0 + cb * GB >= end) break;
            float av[GB];
            if constexpr (VEC == 4) {
                ushort4 hv[GB];
#pragma unroll
                for (int c = 0; c < GB; ++c) {
                    const int ce = cb * GB + c;
                    const int s = __shfl(sm, ce * HN);
                    av[c] = __shfl(am, ce * HN + hl);
                    hv[c] = *reinterpret_cast<const ushort4*>(&hb[(unsigned)s * HC + ch]);
                }
#pragma unroll
                for (int c = 0; c < GB; ++c) {
                    acc[0] += av[c] * bfu(hv[c].x);
                    acc[1] += av[c] * bfu(hv[c].y);
                    acc[2] += av[c] * bfu(hv[c].z);
                    acc[3] += av[c] * bfu(hv[c].w);
                }
            } else {
                unsigned short hv[GB];
#pragma unroll
                for (int c = 0; c < GB; ++c) {
                    const int ce = cb * GB + c;
                    const int s = __shfl(sm, ce * HN);
                    av[c] = __shfl(am, ce * HN + hl);
                    hv[c] = hb[(unsigned)s * HC + ch];
                }
#pragma unroll
                for (int c = 0; c < GB; ++c) acc[0] += av[c] * bfu(hv[c]);
            }
        }
    }

#pragma unroll
    for (int v = 0; v < VEC; ++v) {
        float o = acc[v] + bias[ch + v];
        if (relu) o = fmaxf(o, 0.f);
        acc[v] = o;
    }
    if constexpr (OSPLIT) {
        ushort4 ho, lo4;
        unsigned short h0, l0;
        split1(acc[0], h0, l0); ho.x = h0; lo4.x = l0;
        split1(acc[1], h0, l0); ho.y = h0; lo4.y = l0;
        split1(acc[2], h0, l0); ho.z = h0; lo4.z = l0;
        split1(acc[3], h0, l0); ho.w = h0; lo4.w = l0;
        *reinterpret_cast<ushort4*>(&ohi[(unsigned)n * HC + ch]) = ho;
        *reinterpret_cast<ushort4*>(&olo[(unsigned)n * HC + ch]) = lo4;
    } else if constexpr (VEC == 4) {
        float4 vout;
        vout.x = acc[0]; vout.y = acc[1]; vout.z = acc[2]; vout.w = acc[3];
        *reinterpret_cast<float4*>(&out[(unsigned)n * HC + ch]) = vout;
    } else {
        out[(unsigned)n * HC + ch] = acc[0];
    }
}

// ---------------- layer-3 aggregate: wave-UNIFORM shfl control flow ---------
// HC=64, HN=1. Lane l stashes edge beg+b*64+l. Per uniform block cb, group
// g=l>>4 gathers edges cb*16+g+{0,4,8,12}; invalid edges have stashed p=0 ->
// alpha 0 (contribution zero; address defaults to node 0, cache-hot).
// All __shfl executed by all 64 lanes in uniform flow (the r11 bug fix).
template <int P>
__global__ __launch_bounds__(256) void k_agg7(const unsigned short* __restrict__ hb,
                                              const float* __restrict__ als,
                                              const float* __restrict__ ald,
                                              const int* __restrict__ ptr,
                                              const int* __restrict__ srcs,
                                              const float* __restrict__ bias,
                                              float* __restrict__ out,
                                              int N) {
    constexpr int HC = 64;
    const int l = threadIdx.x & 63;
    const int n = blockIdx.x * 4 + (threadIdx.x >> 6);
    if (n >= N) return;
    const int beg = ptr[n], end = ptr[n + 1];
    const float aldv = ald[n];

    // pass 1: exp-sum + stash (lane l owns edge beg + b*64 + l)
    float p[P];
    int   sr[P];
    float ssum = 0.f;
#pragma unroll
    for (int b = 0; b < P; ++b) {
        const int j = beg + b * 64 + l;
        float pv = 0.f; int s = 0;
        if (j < end) { s = srcs[j]; pv = __expf(leaky(als[s] + aldv)); }
        sr[b] = s; p[b] = pv; ssum += pv;
    }
    for (int j = beg + P * 64 + l; j < end; j += 64)
        ssum += __expf(leaky(als[srcs[j]] + aldv));
#pragma unroll
    for (int o = 1; o < 64; o <<= 1) ssum += __shfl_xor(ssum, o);
    const float inv = 1.f / (ssum + 1e-16f);

    // pass 2 (all loops wave-uniform; shfl sources always active)
    const int grp = l >> 4;
    const int lch = (l & 15) * 4;
    float acc[4] = {0.f, 0.f, 0.f, 0.f};

#pragma unroll
    for (int b = 0; b < P; ++b) {
        const int j0 = beg + b * 64;
        if (j0 >= end) break;                       // uniform
        const float am = p[b] * inv;                // 0 for invalid edges
        const int ned = min(64, end - j0);          // uniform
        const int nblk = (ned + 15) >> 4;           // uniform
        for (int cb = 0; cb < nblk; ++cb) {         // uniform loop
            const int e0 = cb * 16 + grp;
            const float a0 = __shfl(am, e0),       a1 = __shfl(am, e0 + 4);
            const float a2 = __shfl(am, e0 + 8),   a3 = __shfl(am, e0 + 12);
            const int   s0 = __shfl(sr[b], e0),      s1 = __shfl(sr[b], e0 + 4);
            const int   s2 = __shfl(sr[b], e0 + 8),  s3 = __shfl(sr[b], e0 + 12);
            const ushort4 h0 = *reinterpret_cast<const ushort4*>(&hb[(unsigned)s0 * HC + lch]);
            const ushort4 h1 = *reinterpret_cast<const ushort4*>(&hb[(unsigned)s1 * HC + lch]);
            const ushort4 h2 = *reinterpret_cast<const ushort4*>(&hb[(unsigned)s2 * HC + lch]);
            const ushort4 h3 = *reinterpret_cast<const ushort4*>(&hb[(unsigned)s3 * HC + lch]);
            acc[0] += a0 * bfu(h0.x) + a1 * bfu(h1.x) + a2 * bfu(h2.x) + a3 * bfu(h3.x);
            acc[1] += a0 * bfu(h0.y) + a1 * bfu(h1.y) + a2 * bfu(h2.y) + a3 * bfu(h3.y);
            acc[2] += a0 * bfu(h0.z) + a1 * bfu(h1.z) + a2 * bfu(h2.z) + a3 * bfu(h3.z);
            acc[3] += a0 * bfu(h0.w) + a1 * bfu(h1.w) + a2 * bfu(h2.w) + a3 * bfu(h3.w);
        }
    }
    // overflow (degree > P*64): same uniform pattern, alpha recomputed
    for (int j0 = beg + P * 64; j0 < end; j0 += 64) {
        const int j = j0 + l;
        int sm = 0; float am = 0.f;
        if (j < end) { sm = srcs[j]; am = __expf(leaky(als[sm] + aldv)) * inv; }
        const int ned = min(64, end - j0);
        const int nblk = (ned + 15) >> 4;
        for (int cb = 0; cb < nblk; ++cb) {
            const int e0 = cb * 16 + grp;
            const float a0 = __shfl(am, e0),       a1 = __shfl(am, e0 + 4);
            const float a2 = __shfl(am, e0 + 8),   a3 = __shfl(am, e0 + 12);
            const int   s0 = __shfl(sm, e0),       s1 = __shfl(sm, e0 + 4);
            const int   s2 = __shfl(sm, e0 + 8),   s3 = __shfl(sm, e0 + 12);
            const ushort4 h0 = *reinterpret_cast<const ushort4*>(&hb[(unsigned)s0 * HC + lch]);
            const ushort4 h1 = *reinterpret_cast<const ushort4*>(&hb[(unsigned)s1 * HC + lch]);
            const ushort4 h2 = *reinterpret_cast<const ushort4*>(&hb[(unsigned)s2 * HC + lch]);
            const ushort4 h3 = *reinterpret_cast<const ushort4*>(&hb[(unsigned)s3 * HC + lch]);
            acc[0] += a0 * bfu(h0.x) + a1 * bfu(h1.x) + a2 * bfu(h2.x) + a3 * bfu(h3.x);
            acc[1] += a0 * bfu(h0.y) + a1 * bfu(h1.y) + a2 * bfu(h2.y) + a3 * bfu(h3.y);
            acc[2] += a0 * bfu(h0.z) + a1 * bfu(h1.z) + a2 * bfu(h2.z) + a3 * bfu(h3.z);
            acc[3] += a0 * bfu(h0.w) + a1 * bfu(h1.w) + a2 * bfu(h2.w) + a3 * bfu(h3.w);
        }
    }

    // cross-group reduce (groups hold disjoint edge subsets of same channels)
#pragma unroll
    for (int o = 16; o < 64; o <<= 1) {
#pragma unroll
        for (int v = 0; v < 4; ++v) acc[v] += __shfl_xor(acc[v], o);
    }

    if (l < 16) {
        float4 vout;
        vout.x = acc[0] + bias[lch + 0];
        vout.y = acc[1] + bias[lch + 1];
        vout.z = acc[2] + bias[lch + 2];
        vout.w = acc[3] + bias[lch + 3];
        *reinterpret_cast<float4*>(&out[(size_t)n * HC + lch]) = vout;
    }
}

// ---------------- launch ----------------

extern "C" void kernel_launch(void* const* d_in, const int* in_sizes, int n_in,
                              void* d_out, int out_size, void* d_ws, size_t ws_size,
                              hipStream_t stream) {
    const float* x   = (const float*)d_in[0];
    const int*   ei  = (const int*)d_in[1];
    const float* W1  = (const float*)d_in[2];
    const float* as1 = (const float*)d_in[3];
    const float* ad1 = (const float*)d_in[4];
    const float* b1  = (const float*)d_in[5];
    const float* W2  = (const float*)d_in[6];
    const float* as2 = (const float*)d_in[7];
    const float* ad2 = (const float*)d_in[8];
    const float* b2  = (const float*)d_in[9];
    const float* W3  = (const float*)d_in[10];
    const float* as3 = (const float*)d_in[11];
    const float* ad3 = (const float*)d_in[12];
    const float* b3  = (const float*)d_in[13];

    const int F  = 256;
    const int N  = in_sizes[0] / F;     // 50000
    const int E  = in_sizes[1] / 2;     // 800000
    const int Et = E + N;

    char* w = (char*)d_ws;
    auto alloc = [&](size_t bytes) {
        char* p = w;
        w += (bytes + 255) & ~(size_t)255;
        return p;
    };
    unsigned short* S0hi = (unsigned short*)alloc((size_t)N * F * 2);
    unsigned short* S0lo = (unsigned short*)alloc((size_t)N * F * 2);
    unsigned short* S1hi = (unsigned short*)alloc((size_t)N * F * 2);
    unsigned short* S1lo = (unsigned short*)alloc((size_t)N * F * 2);
    unsigned short* hB   = (unsigned short*)alloc((size_t)N * F * 2);
    unsigned short* Wt1hi = (unsigned short*)alloc((size_t)256 * 256 * 2);
    unsigned short* Wt1lo = (unsigned short*)alloc((size_t)256 * 256 * 2);
    unsigned short* Wt2hi = (unsigned short*)alloc((size_t)256 * 256 * 2);
    unsigned short* Wt2lo = (unsigned short*)alloc((size_t)256 * 256 * 2);
    unsigned short* Wt3hi = (unsigned short*)alloc((size_t)64 * 256 * 2);
    unsigned short* Wt3lo = (unsigned short*)alloc((size_t)64 * 256 * 2);
    float* als  = (float*)alloc((size_t)N * 8 * 4);
    float* ald  = (float*)alloc((size_t)N * 8 * 4);
    int*   cnt  = (int*)alloc((size_t)N * 4);
    int*   ptr  = (int*)alloc((size_t)(N + 1) * 4);
    int*   fptr = (int*)alloc((size_t)(N + 1) * 4);
    int*   srcs = (int*)alloc((size_t)Et * 4);
    int*   bsum = (int*)alloc(4096);

    const int n8 = N * F / 8;
    const int nset = (N + 255) / 256;
    const int nsplit = (n8 + 255) / 256;
    const int nprep = nset + nsplit + 64 + 64 + 16;

    hipLaunchKernelGGL(k_prep, dim3(nprep), dim3(256), 0, stream,
                       cnt, N, x, S0hi, S0lo, n8,
                       W1, Wt1hi, Wt1lo, W2, Wt2hi, Wt2lo, W3, Wt3hi, Wt3lo,
                       nset, nsplit);

    const int nb = (N + 1023) / 1024;
    hipLaunchKernelGGL(k_count,     dim3((E + 255) / 256),  dim3(256), 0, stream, ei + E, cnt, E);
    hipLaunchKernelGGL(k_scan_local,dim3(nb),               dim3(256), 0, stream, cnt, ptr, bsum, N);
    hipLaunchKernelGGL(k_scan_add2, dim3((N + 256) / 256),  dim3(256), 0, stream, ptr, bsum, N, Et);
    hipLaunchKernelGGL(k_copy,      dim3((N + 255) / 256),  dim3(256), 0, stream, fptr, ptr, N);
    hipLaunchKernelGGL(k_fillcsr,   dim3((Et + 255) / 256), dim3(256), 0, stream, ei, fptr, srcs, E, Et);

    const dim3 gN4((N + 3) / 4);
    const int gx = (N + 63) / 64;

    // ---- layer 1 ----
    hipLaunchKernelGGL(k_gemm2, dim3(gx), dim3(256), 0, stream,
                       S0hi, S0lo, Wt1hi, Wt1lo, as1, ad1, hB, als, ald, N);
    hipLaunchKernelGGL((k_agg6<8, 32, 4, 8, true>), gN4, dim3(256), 0, stream,
                       hB, als, ald, ptr, srcs, b1, S1hi, S1lo, nullptr, N, 1);
    // ---- layer 2 ----
    hipLaunchKernelGGL(k_gemm2, dim3(gx), dim3(256), 0, stream,
                       S1hi, S1lo, Wt2hi, Wt2lo, as2, ad2, hB, als, ald, N);
    hipLaunchKernelGGL((k_agg6<8, 32, 4, 8, true>), gN4, dim3(256), 0, stream,
                       hB, als, ald, ptr, srcs, b2, S0hi, S0lo, nullptr, N, 1);
    // ---- layer 3 ----
    hipLaunchKernelGGL((k_gemm_s<1, 64>), dim3(gx, 1), dim3(256), 0, stream,
                       S0hi, S0lo, Wt3hi, Wt3lo, as3, ad3, hB, als, ald, N);
    hipLaunchKernelGGL((k_agg7<2>), gN4, dim3(256), 0, stream,
                       hB, als, ald, ptr, srcs, b3, (float*)d_out, N);
}